// Round 6
// baseline (2592.572 us; speedup 1.0000x reference)
//
#include <hip/hip_runtime.h>
#include <stdint.h>

// ---------------- bf16 helpers (raw ushort storage) ----------------
__device__ __forceinline__ float bflo(unsigned int u) {
    union { unsigned int u; float f; } c; c.u = u << 16; return c.f;
}
__device__ __forceinline__ float bfhi(unsigned int u) {
    union { unsigned int u; float f; } c; c.u = u & 0xffff0000u; return c.f;
}
__device__ __forceinline__ unsigned int f2bf(float f) {
    union { float f; unsigned int u; } c; c.f = f;
    unsigned int u = c.u;
    u += 0x7fffu + ((u >> 16) & 1u);   // round-to-nearest-even
    return u >> 16;
}
__device__ __forceinline__ unsigned int packbf(float a, float b) {
    return f2bf(a) | (f2bf(b) << 16);
}

typedef __attribute__((ext_vector_type(8))) short s8v;   // 8 bf16 (4 VGPRs)
typedef __attribute__((ext_vector_type(4))) float f4v;   // MFMA accumulator

__device__ __forceinline__ f4v mfma16(s8v a, s8v b, f4v c) {
    return __builtin_amdgcn_mfma_f32_16x16x32_bf16(a, b, c, 0, 0, 0);
}

// ---------------- counting-sort parameters ----------------
#define RANGE_BITS 14
#define RANGE (1 << RANGE_BITS)     // 16384 nodes per LDS range (32 KB @ 2B/node)
#define NR_PAD 8                    // ranges padded to 8 for XCD swizzle (range = bid & 7)
#define NSLICE 64                   // edge slices; per-slice count <= E/64 = 25000 < 2^16

// ---------------- spmm tiling parameters ----------------
#define SROWS 64                    // dst rows per block (f32 acc tile in LDS)
#define SPAD 132                    // padded row stride (bank-conflict-free epilogue)
#define CAP 1536                    // bucketed edge capacity (Poisson(1024)+16 sigma)
#define NBUCK 32                    // src buckets (src >> 12 : 4096-row ~1MB windows)
#define BSHIFT 12

// ---------------- weight prep: W[k][n] f32 -> Wt[n][k] bf16 ----------------
__global__ __launch_bounds__(256) void k_prep_w(const float* __restrict__ W1,
                                                const float* __restrict__ W2,
                                                const float* __restrict__ Wr,
                                                unsigned short* __restrict__ Wt) {
    const float* W = (blockIdx.x == 0) ? W1 : (blockIdx.x == 1) ? W2 : Wr;
    unsigned short* T = Wt + (size_t)blockIdx.x * 16384;
    const int wv = threadIdx.x >> 6, l = threadIdx.x & 63;
    const int kb = blockIdx.y * 32 + wv * 8;
#pragma unroll
    for (int half = 0; half < 2; ++half) {
        const int n = l + half * 64;
        unsigned short tmp[8];
#pragma unroll
        for (int j = 0; j < 8; ++j) tmp[j] = (unsigned short)f2bf(W[(size_t)(kb + j) * 128 + n]);
#pragma unroll
        for (int j = 0; j < 8; j += 2)
            *(unsigned int*)&T[(size_t)n * 128 + kb + j] =
                (unsigned int)tmp[j] | ((unsigned int)tmp[j + 1] << 16);
    }
}

// ---------------- LDS-privatized degree histogram (no global atomics) ----------------
__global__ __launch_bounds__(256) void k_hist_lds(const int* __restrict__ src,
                                                  const int* __restrict__ dst,
                                                  unsigned int* __restrict__ partialS,
                                                  unsigned int* __restrict__ partialD,
                                                  int E, int EPS) {
    __shared__ unsigned int cnt[RANGE / 2];   // 32 KB
    const int r = blockIdx.x & 7;
    const int s = blockIdx.x >> 3;
    const int a = blockIdx.y;
    const int* __restrict__ arr = a ? dst : src;
    unsigned int* part = (a ? partialD : partialS)
                         + ((size_t)r * NSLICE + s) * (RANGE / 2);
    for (int i = threadIdx.x; i < RANGE / 2; i += 256) cnt[i] = 0;
    __syncthreads();
    const int e0 = s * EPS;
    const int e1 = min(E, e0 + EPS);
    int e = e0 + threadIdx.x * 4;
    for (; e + 3 < e1; e += 1024) {
        const int4 v = *(const int4*)&arr[e];
        if ((v.x >> RANGE_BITS) == r) { int l = v.x & (RANGE - 1); atomicAdd(&cnt[l >> 1], 1u << ((l & 1) << 4)); }
        if ((v.y >> RANGE_BITS) == r) { int l = v.y & (RANGE - 1); atomicAdd(&cnt[l >> 1], 1u << ((l & 1) << 4)); }
        if ((v.z >> RANGE_BITS) == r) { int l = v.z & (RANGE - 1); atomicAdd(&cnt[l >> 1], 1u << ((l & 1) << 4)); }
        if ((v.w >> RANGE_BITS) == r) { int l = v.w & (RANGE - 1); atomicAdd(&cnt[l >> 1], 1u << ((l & 1) << 4)); }
    }
    for (; e < e1; ++e) {
        const int idx = arr[e];
        if ((idx >> RANGE_BITS) == r) { int l = idx & (RANGE - 1); atomicAdd(&cnt[l >> 1], 1u << ((l & 1) << 4)); }
    }
    __syncthreads();
    for (int i = threadIdx.x; i < RANGE / 2; i += 256) part[i] = cnt[i];
}

// ---------------- reduce partials -> degrees/norms; dst partials -> slice prefixes ----------------
__global__ __launch_bounds__(256) void k_deg_reduce(unsigned int* __restrict__ pS,
                                                    unsigned int* __restrict__ pD,
                                                    float* __restrict__ out_norm,
                                                    float* __restrict__ in_norm,
                                                    int* __restrict__ in_deg, int N) {
    const int a = blockIdx.y;
    const int t = blockIdx.x * 256 + threadIdx.x;
    const int r = t >> (RANGE_BITS - 1);
    const int w = t & ((RANGE / 2) - 1);
    unsigned int* base = (a ? pD : pS) + (size_t)r * NSLICE * (RANGE / 2) + w;
    unsigned int lo = 0, hi = 0;
    if (a) {
        for (int s = 0; s < NSLICE; ++s) {
            const unsigned int v = base[(size_t)s * (RANGE / 2)];
            base[(size_t)s * (RANGE / 2)] = lo | (hi << 16);
            lo += v & 0xffffu; hi += v >> 16;
        }
    } else {
        for (int s = 0; s < NSLICE; ++s) {
            const unsigned int v = base[(size_t)s * (RANGE / 2)];
            lo += v & 0xffffu; hi += v >> 16;
        }
    }
    const int n0 = r * RANGE + 2 * w, n1 = n0 + 1;
    if (a) {
        if (n0 < N) { in_deg[n0] = (int)lo; in_norm[n0] = rsqrtf(fmaxf((float)lo, 1.f)); }
        if (n1 < N) { in_deg[n1] = (int)hi; in_norm[n1] = rsqrtf(fmaxf((float)hi, 1.f)); }
    } else {
        if (n0 < N) out_norm[n0] = rsqrtf(fmaxf((float)lo, 1.f));
        if (n1 < N) out_norm[n1] = rsqrtf(fmaxf((float)hi, 1.f));
    }
}

// ---------------- prefix-sum (3-phase) ----------------
__global__ __launch_bounds__(1024) void k_scan_block(const int* __restrict__ in,
                                                     int* __restrict__ row_ptr,
                                                     int* __restrict__ partials, int n) {
    __shared__ int sh[1024];
    int i = blockIdx.x * 1024 + threadIdx.x;
    int v = (i < n) ? in[i] : 0;
    sh[threadIdx.x] = v;
    __syncthreads();
    for (int off = 1; off < 1024; off <<= 1) {
        int t = (threadIdx.x >= off) ? sh[threadIdx.x - off] : 0;
        __syncthreads();
        sh[threadIdx.x] += t;
        __syncthreads();
    }
    if (i < n) row_ptr[i + 1] = sh[threadIdx.x];
    if (threadIdx.x == 1023) partials[blockIdx.x] = sh[1023];
}

__global__ __launch_bounds__(1024) void k_scan_partials(int* __restrict__ partials, int nb) {
    __shared__ int sh[1024];
    int v = (threadIdx.x < nb) ? partials[threadIdx.x] : 0;
    sh[threadIdx.x] = v;
    __syncthreads();
    for (int off = 1; off < 1024; off <<= 1) {
        int t = (threadIdx.x >= off) ? sh[threadIdx.x - off] : 0;
        __syncthreads();
        sh[threadIdx.x] += t;
        __syncthreads();
    }
    if (threadIdx.x < nb) partials[threadIdx.x] = sh[threadIdx.x] - v;
}

__global__ void k_scan_finalize(int* __restrict__ row_ptr, const int* __restrict__ partials,
                                int n) {
    int i = blockIdx.x * blockDim.x + threadIdx.x;
    if (i < n) {
        row_ptr[i + 1] += partials[i >> 10];
        if (i == 0) row_ptr[0] = 0;
    }
}

// ---------------- deterministic CSR scatter (no global atomics) ----------------
__global__ __launch_bounds__(256) void k_scatter_lds(const int* __restrict__ src,
                                                     const int* __restrict__ dst,
                                                     const unsigned int* __restrict__ pD,
                                                     const int* __restrict__ row_ptr,
                                                     int* __restrict__ ssrc, int E, int EPS) {
    __shared__ unsigned int cur[RANGE / 2];   // 32 KB
    const int r = blockIdx.x & 7;
    const int s = blockIdx.x >> 3;
    const unsigned int* pre = pD + ((size_t)r * NSLICE + s) * (RANGE / 2);
    for (int i = threadIdx.x; i < RANGE / 2; i += 256) cur[i] = pre[i];
    __syncthreads();
    const int e0 = s * EPS;
    const int e1 = min(E, e0 + EPS);
    int e = e0 + threadIdx.x * 4;
    for (; e + 3 < e1; e += 1024) {
        const int4 v = *(const int4*)&dst[e];
#pragma unroll
        for (int j = 0; j < 4; ++j) {
            const int d = (&v.x)[j];
            if ((d >> RANGE_BITS) == r) {
                const int local = d & (RANGE - 1);
                const int sh = (local & 1) << 4;
                const unsigned int old = atomicAdd(&cur[local >> 1], 1u << sh);
                const unsigned int off = (old >> sh) & 0xffffu;
                ssrc[row_ptr[d] + (int)off] = src[e + j];
            }
        }
    }
    for (; e < e1; ++e) {
        const int d = dst[e];
        if ((d >> RANGE_BITS) == r) {
            const int local = d & (RANGE - 1);
            const int sh = (local & 1) << 4;
            const unsigned int old = atomicAdd(&cur[local >> 1], 1u << sh);
            const unsigned int off = (old >> sh) & 0xffffu;
            ssrc[row_ptr[d] + (int)off] = src[e];
        }
    }
}

// ---------------- MFMA GEMM: out_w[N,128](bf16) = rowscale?(X @ W_w) ----------------
template <typename TIN, int NW, bool SCALE0>
__global__ __launch_bounds__(256) void gemm_mfma(const TIN* __restrict__ X,
                                                 const unsigned short* __restrict__ Wt0,
                                                 const unsigned short* __restrict__ Wt1,
                                                 const float* __restrict__ scale,
                                                 unsigned short* __restrict__ out0,
                                                 unsigned short* __restrict__ out1,
                                                 int N) {
    __shared__ unsigned short Ws[NW][128 * 128];   // 32 KB per weight (64 KB max)
    const int tid = threadIdx.x;
#pragma unroll
    for (int w = 0; w < NW; ++w) {
        const unsigned short* Wsrc = w ? Wt1 : Wt0;
        for (int i = tid; i < 2048; i += 256) {
            const int n = i >> 4, b = i & 15;
            const uint4 v = *(const uint4*)&Wsrc[(size_t)n * 128 + b * 8];
            *(uint4*)&Ws[w][n * 128 + ((b ^ (n & 15)) << 3)] = v;
        }
    }
    __syncthreads();

    const int lane = tid & 63;
    const int wave = tid >> 6;
    const int quad = lane >> 4;
    const int l16 = lane & 15;
    const int r_base = blockIdx.x * 64 + wave * 16;
    const int ra = min(r_base + l16, N - 1);          // A-operand row (clamped)

    f4v acc[NW][8];
#pragma unroll
    for (int w = 0; w < NW; ++w)
#pragma unroll
        for (int nn = 0; nn < 8; ++nn) acc[w][nn] = (f4v)0.f;

    const TIN* xp = X + (size_t)ra * 128 + quad * 8;

#pragma unroll
    for (int kt = 0; kt < 4; ++kt) {
        s8v af;
        if constexpr (sizeof(TIN) == 4) {
            const float4 lo = *(const float4*)(xp + kt * 32);
            const float4 hi = *(const float4*)(xp + kt * 32 + 4);
            af[0] = (short)f2bf(lo.x); af[1] = (short)f2bf(lo.y);
            af[2] = (short)f2bf(lo.z); af[3] = (short)f2bf(lo.w);
            af[4] = (short)f2bf(hi.x); af[5] = (short)f2bf(hi.y);
            af[6] = (short)f2bf(hi.z); af[7] = (short)f2bf(hi.w);
        } else {
            af = *(const s8v*)(xp + kt * 32);
        }
#pragma unroll
        for (int nn = 0; nn < 8; ++nn) {
            const int bofs = (nn * 16 + l16) * 128 + (((kt * 4 + quad) ^ l16) << 3);
#pragma unroll
            for (int w = 0; w < NW; ++w) {
                const s8v bf = *(const s8v*)&Ws[w][bofs];
                acc[w][nn] = mfma16(af, bf, acc[w][nn]);
            }
        }
    }

    // epilogue: C/D layout col = lane&15, row = quad*4 + reg
    const int rc = r_base + quad * 4;
    float sc[4];
    if constexpr (SCALE0) {
#pragma unroll
        for (int g = 0; g < 4; ++g) sc[g] = scale[min(rc + g, N - 1)];
    }
#pragma unroll
    for (int nn = 0; nn < 8; ++nn) {
        const int col = nn * 16 + l16;
#pragma unroll
        for (int g = 0; g < 4; ++g) {
            const int r = rc + g;
            if (r < N) {
                float v0 = acc[0][nn][g];
                if constexpr (SCALE0) v0 *= sc[g];
                out0[(size_t)r * 128 + col] = (unsigned short)f2bf(v0);
                if constexpr (NW == 2)
                    out1[(size_t)r * 128 + col] = (unsigned short)f2bf(acc[1][nn][g]);
            }
        }
    }
}

// ---------------- CSR aggregation: bucketed phase-coherent gather ----------------
// Block = 64 dst rows, f32 acc tile in LDS (padded stride 132). Edge segment is
// radix-partitioned into 32 src-buckets (~1MB windows); all resident blocks walk
// buckets in ascending order -> chip-wide gather working set stays L2-resident.
template <int FINAL>
__global__ __launch_bounds__(256) void spmm_agg(const unsigned short* __restrict__ T,
                                                const int* __restrict__ row_ptr,
                                                const int* __restrict__ ssrc,
                                                const float* __restrict__ in_norm,
                                                const float* __restrict__ bias,
                                                unsigned short* __restrict__ Hout,
                                                const unsigned short* __restrict__ Res,
                                                const float* __restrict__ mlpW,
                                                const float* __restrict__ mlpB,
                                                float* __restrict__ out, int N) {
    __shared__ float acc[SROWS][SPAD];        // 33792 B
    __shared__ unsigned int earr[CAP];        // 6144 B
    __shared__ int rp[SROWS + 1];             // 260 B
    __shared__ int boff[NBUCK];               // 128 B
    __shared__ int bcur[NBUCK];               // 128 B

    const int tid = threadIdx.x;
    const int d0 = blockIdx.x * SROWS;

    for (int i = tid; i <= SROWS; i += 256) rp[i] = row_ptr[min(d0 + i, N)];
    for (int i = tid; i < SROWS * SPAD; i += 256) ((float*)acc)[i] = 0.f;
    if (tid < NBUCK) boff[tid] = 0;
    __syncthreads();

    const int start = rp[0];
    const int seg = rp[SROWS] - start;
    const int nb = min(seg, CAP);

    // phase 1a: bucket histogram
    for (int i = tid; i < nb; i += 256)
        atomicAdd(&boff[ssrc[start + i] >> BSHIFT], 1);
    __syncthreads();
    if (tid == 0) {
        int run = 0;
        for (int b = 0; b < NBUCK; ++b) { int h = boff[b]; boff[b] = run; bcur[b] = run; run += h; }
    }
    __syncthreads();

    // phase 1b: scatter (src<<6 | local_row) into bucket-major order
    for (int i = tid; i < nb; i += 256) {
        const int e = start + i;
        const int s = ssrc[e];
        int lo = 0, hi = SROWS;
        while (hi - lo > 1) { const int mid = (lo + hi) >> 1; if (e >= rp[mid]) lo = mid; else hi = mid; }
        const int pos = atomicAdd(&bcur[s >> BSHIFT], 1);
        earr[pos] = ((unsigned int)s << 6) | (unsigned int)lo;
    }
    __syncthreads();

    // phase 2: gather + LDS f32 accumulate, bucket-major (16 lanes per edge)
    const int grp = tid >> 4, gl = tid & 15;
    for (int i = grp; i < nb; i += 16) {
        const unsigned int v = earr[i];
        const int s = (int)(v >> 6), lr = (int)(v & 63u);
        const uint4 w = *(const uint4*)&T[(size_t)s * 128 + gl * 8];
        float* ap = &acc[lr][gl * 8];
        atomicAdd(&ap[0], bflo(w.x)); atomicAdd(&ap[1], bfhi(w.x));
        atomicAdd(&ap[2], bflo(w.y)); atomicAdd(&ap[3], bfhi(w.y));
        atomicAdd(&ap[4], bflo(w.z)); atomicAdd(&ap[5], bfhi(w.z));
        atomicAdd(&ap[6], bflo(w.w)); atomicAdd(&ap[7], bfhi(w.w));
    }
    // overflow path (statistically dead; correctness safety for seg > CAP)
    for (int i = CAP + grp; i < seg; i += 16) {
        const int e = start + i;
        const int s = ssrc[e];
        int lo = 0, hi = SROWS;
        while (hi - lo > 1) { const int mid = (lo + hi) >> 1; if (e >= rp[mid]) lo = mid; else hi = mid; }
        const uint4 w = *(const uint4*)&T[(size_t)s * 128 + gl * 8];
        float* ap = &acc[lo][gl * 8];
        atomicAdd(&ap[0], bflo(w.x)); atomicAdd(&ap[1], bfhi(w.x));
        atomicAdd(&ap[2], bflo(w.y)); atomicAdd(&ap[3], bfhi(w.y));
        atomicAdd(&ap[4], bflo(w.z)); atomicAdd(&ap[5], bfhi(w.z));
        atomicAdd(&ap[6], bflo(w.w)); atomicAdd(&ap[7], bfhi(w.w));
    }
    __syncthreads();

    // phase 3: epilogue — 4 threads per row, 32 cols each
    const int r = tid >> 2, q = tid & 3;
    const int dd = d0 + r;
    if (dd >= N) return;
    const float inr = in_norm[dd];
    const float* ap = &acc[r][q * 32];
    float v[32];
#pragma unroll
    for (int j = 0; j < 32; ++j) v[j] = ap[j] * inr + bias[q * 32 + j];

    if constexpr (FINAL == 0) {
#pragma unroll
        for (int j = 0; j < 32; ++j) v[j] = fmaxf(v[j], 0.f);
        uint4 o[2];
#pragma unroll
        for (int h = 0; h < 2; ++h) {
            o[h].x = packbf(v[h * 16 + 0], v[h * 16 + 1]);
            o[h].y = packbf(v[h * 16 + 2], v[h * 16 + 3]);
            o[h].z = packbf(v[h * 16 + 4], v[h * 16 + 5]);
            o[h].w = packbf(v[h * 16 + 6], v[h * 16 + 7]);
        }
        // two uint4 = 16 bf16 each? (uint4 = 8 bf16) -> need 4 stores of 8 cols
        const unsigned short* vdummy = nullptr; (void)vdummy;
        // pack remaining halves
        uint4 o2[2];
#pragma unroll
        for (int h = 0; h < 2; ++h) {
            o2[h].x = packbf(v[h * 16 + 8], v[h * 16 + 9]);
            o2[h].y = packbf(v[h * 16 + 10], v[h * 16 + 11]);
            o2[h].z = packbf(v[h * 16 + 12], v[h * 16 + 13]);
            o2[h].w = packbf(v[h * 16 + 14], v[h * 16 + 15]);
        }
        unsigned short* hp = &Hout[(size_t)dd * 128 + q * 32];
        *(uint4*)&hp[0]  = o[0];
        *(uint4*)&hp[8]  = o2[0];
        *(uint4*)&hp[16] = o[1];
        *(uint4*)&hp[24] = o2[1];
    } else {
        const unsigned short* rp2 = &Res[(size_t)dd * 128 + q * 32];
#pragma unroll
        for (int c = 0; c < 4; ++c) {
            const uint4 rw = *(const uint4*)&rp2[c * 8];
            v[c * 8 + 0] += bflo(rw.x); v[c * 8 + 1] += bfhi(rw.x);
            v[c * 8 + 2] += bflo(rw.y); v[c * 8 + 3] += bfhi(rw.y);
            v[c * 8 + 4] += bflo(rw.z); v[c * 8 + 5] += bfhi(rw.z);
            v[c * 8 + 6] += bflo(rw.w); v[c * 8 + 7] += bfhi(rw.w);
        }
        const float4* mwp = (const float4*)&mlpW[q * 64];
        float p0 = 0.f, p1 = 0.f;
#pragma unroll
        for (int t = 0; t < 16; ++t) {
            const float4 mw = mwp[t];
            p0 = fmaf(v[2 * t], mw.x, p0);     p1 = fmaf(v[2 * t], mw.y, p1);
            p0 = fmaf(v[2 * t + 1], mw.z, p0); p1 = fmaf(v[2 * t + 1], mw.w, p1);
        }
        p0 += __shfl_xor(p0, 1); p1 += __shfl_xor(p1, 1);
        p0 += __shfl_xor(p0, 2); p1 += __shfl_xor(p1, 2);
        if (q == 0) {
            out[(size_t)dd * 2 + 0] = p0 + mlpB[0];
            out[(size_t)dd * 2 + 1] = p1 + mlpB[1];
        }
    }
}

// ---------------- launch ----------------
extern "C" void kernel_launch(void* const* d_in, const int* in_sizes, int n_in,
                              void* d_out, int out_size, void* d_ws, size_t ws_size,
                              hipStream_t stream) {
    const float* x     = (const float*)d_in[0];
    const int*   src   = (const int*)d_in[1];
    const int*   dst   = (const int*)d_in[2];
    const float* W1    = (const float*)d_in[3];
    const float* b1    = (const float*)d_in[4];
    const float* W2    = (const float*)d_in[5];
    const float* b2    = (const float*)d_in[6];
    const float* res_W = (const float*)d_in[7];
    const float* mlp_W = (const float*)d_in[8];
    const float* mlp_b = (const float*)d_in[9];
    float* out = (float*)d_out;

    const int N = in_sizes[0] / 128;
    const int E = in_sizes[1];
    const int EPS = (E + NSLICE - 1) / NSLICE;

    // workspace layout. partialS aliases A, partialD aliases C: both are dead
    // before the first GEMM writes A/C (deg_reduce & scatter consume them earlier).
    char* p = (char*)d_ws;
    unsigned short* A = (unsigned short*)p;  p += (size_t)N * 128 * 2;   // t1 / t2
    unsigned short* B = (unsigned short*)p;  p += (size_t)N * 128 * 2;   // h1
    unsigned short* C = (unsigned short*)p;  p += (size_t)N * 128 * 2;   // res (aliases partialD)
    unsigned short* Wt = (unsigned short*)p; p += (size_t)3 * 16384 * 2; // Wt1|Wt2|Rt bf16
    float* out_norm = (float*)p;             p += (size_t)N * 4;
    float* in_norm  = (float*)p;             p += (size_t)N * 4;
    int* in_deg     = (int*)p;               p += (size_t)N * 4;
    int* row_ptr    = (int*)p;               p += (size_t)(N + 1) * 4;
    int* scanpart   = (int*)p;               p += (size_t)1024 * 4;
    int* ssrc       = (int*)p;               p += (size_t)E * 4;
    unsigned int* partialS = (unsigned int*)A;
    unsigned int* partialD = (unsigned int*)C;

    const int gN = (N + 255) / 256;
    const int nb = (N + 1023) / 1024;
    const int gGemm = (N + 63) / 64;
    const int gSpmm = (N + SROWS - 1) / SROWS;

    // 0. weights -> transposed bf16
    k_prep_w<<<dim3(3, 4), 256, 0, stream>>>(W1, W2, res_W, Wt);

    // 1. degrees + norms + slice prefixes (no global atomics)
    k_hist_lds<<<dim3(NR_PAD * NSLICE, 2), 256, 0, stream>>>(src, dst, partialS, partialD, E, EPS);
    k_deg_reduce<<<dim3(NR_PAD * (RANGE / 2) / 256, 2), 256, 0, stream>>>(partialS, partialD,
                                                                          out_norm, in_norm, in_deg, N);

    // 2. row_ptr scan + deterministic CSR scatter
    k_scan_block<<<nb, 1024, 0, stream>>>(in_deg, row_ptr, scanpart, N);
    k_scan_partials<<<1, 1024, 0, stream>>>(scanpart, nb);
    k_scan_finalize<<<gN, 256, 0, stream>>>(row_ptr, scanpart, N);
    k_scatter_lds<<<NR_PAD * NSLICE, 256, 0, stream>>>(src, dst, partialD, row_ptr, ssrc, E, EPS);

    // 3. fused gemm1+gemm3: A = rowscale(x@W1, out_norm), C = x@res_W
    gemm_mfma<float, 2, true><<<gGemm, 256, 0, stream>>>(x, Wt, Wt + 2 * 16384, out_norm, A, C, N);

    // 4. layer-1 aggregation: B = relu(agg(A)*in_norm + b1)
    spmm_agg<0><<<gSpmm, 256, 0, stream>>>(A, row_ptr, ssrc, in_norm, b1, B,
                                           (const unsigned short*)nullptr, nullptr, nullptr,
                                           nullptr, N);

    // 5. gemm2: A = rowscale(B@W2, out_norm)
    gemm_mfma<unsigned short, 1, true><<<gGemm, 256, 0, stream>>>(B, Wt + 16384, nullptr,
                                                                  out_norm, A, nullptr, N);

    // 6. final aggregation + residual + MLP head -> out
    spmm_agg<1><<<gSpmm, 256, 0, stream>>>(A, row_ptr, ssrc, in_norm, b2, nullptr,
                                           C, mlp_W, mlp_b, out, N);

    (void)n_in; (void)out_size; (void)ws_size;
}

// Round 7
// 333.876 us; speedup vs baseline: 7.7651x; 7.7651x over previous
//
#include <hip/hip_runtime.h>
#include <stdint.h>

// ---------------- bf16 helpers (raw ushort storage) ----------------
__device__ __forceinline__ float bflo(unsigned int u) {
    union { unsigned int u; float f; } c; c.u = u << 16; return c.f;
}
__device__ __forceinline__ float bfhi(unsigned int u) {
    union { unsigned int u; float f; } c; c.u = u & 0xffff0000u; return c.f;
}
__device__ __forceinline__ unsigned int f2bf(float f) {
    union { float f; unsigned int u; } c; c.f = f;
    unsigned int u = c.u;
    u += 0x7fffu + ((u >> 16) & 1u);   // round-to-nearest-even
    return u >> 16;
}
__device__ __forceinline__ unsigned int packbf(float a, float b) {
    return f2bf(a) | (f2bf(b) << 16);
}

typedef __attribute__((ext_vector_type(8))) short s8v;   // 8 bf16 (4 VGPRs)
typedef __attribute__((ext_vector_type(4))) float f4v;   // MFMA accumulator
typedef __attribute__((ext_vector_type(2))) float f2v;   // fp8 unpack pair

__device__ __forceinline__ f4v mfma16(s8v a, s8v b, f4v c) {
    return __builtin_amdgcn_mfma_f32_16x16x32_bf16(a, b, c, 0, 0, 0);
}

// fp8 e4m3 (OCP) pack/unpack via gfx950 HW converters
__device__ __forceinline__ unsigned char f2fp8(float v) {
    return (unsigned char)(__builtin_amdgcn_cvt_pk_fp8_f32(v, v, 0, false) & 0xff);
}

// ---------------- counting-sort parameters ----------------
#define RANGE_BITS 14
#define RANGE (1 << RANGE_BITS)     // 16384 nodes per LDS range (32 KB @ 2B/node)
#define NR_PAD 8                    // ranges padded to 8 for XCD swizzle (range = bid & 7)
#define NSLICE 64                   // edge slices; per-slice count <= E/64 = 25000 < 2^16

// ---------------- weight prep: W[k][n] f32 -> Wt[n][k] bf16 ----------------
__global__ __launch_bounds__(256) void k_prep_w(const float* __restrict__ W1,
                                                const float* __restrict__ W2,
                                                const float* __restrict__ Wr,
                                                unsigned short* __restrict__ Wt) {
    const float* W = (blockIdx.x == 0) ? W1 : (blockIdx.x == 1) ? W2 : Wr;
    unsigned short* T = Wt + (size_t)blockIdx.x * 16384;
    const int wv = threadIdx.x >> 6, l = threadIdx.x & 63;
    const int kb = blockIdx.y * 32 + wv * 8;
#pragma unroll
    for (int half = 0; half < 2; ++half) {
        const int n = l + half * 64;
        unsigned short tmp[8];
#pragma unroll
        for (int j = 0; j < 8; ++j) tmp[j] = (unsigned short)f2bf(W[(size_t)(kb + j) * 128 + n]);
#pragma unroll
        for (int j = 0; j < 8; j += 2)
            *(unsigned int*)&T[(size_t)n * 128 + kb + j] =
                (unsigned int)tmp[j] | ((unsigned int)tmp[j + 1] << 16);
    }
}

// ---------------- LDS-privatized degree histogram (no global atomics) ----------------
__global__ __launch_bounds__(256) void k_hist_lds(const int* __restrict__ src,
                                                  const int* __restrict__ dst,
                                                  unsigned int* __restrict__ partialS,
                                                  unsigned int* __restrict__ partialD,
                                                  int E, int EPS) {
    __shared__ unsigned int cnt[RANGE / 2];   // 32 KB
    const int r = blockIdx.x & 7;
    const int s = blockIdx.x >> 3;
    const int a = blockIdx.y;
    const int* __restrict__ arr = a ? dst : src;
    unsigned int* part = (a ? partialD : partialS)
                         + ((size_t)r * NSLICE + s) * (RANGE / 2);
    for (int i = threadIdx.x; i < RANGE / 2; i += 256) cnt[i] = 0;
    __syncthreads();
    const int e0 = s * EPS;
    const int e1 = min(E, e0 + EPS);
    int e = e0 + threadIdx.x * 4;
    for (; e + 3 < e1; e += 1024) {
        const int4 v = *(const int4*)&arr[e];
        if ((v.x >> RANGE_BITS) == r) { int l = v.x & (RANGE - 1); atomicAdd(&cnt[l >> 1], 1u << ((l & 1) << 4)); }
        if ((v.y >> RANGE_BITS) == r) { int l = v.y & (RANGE - 1); atomicAdd(&cnt[l >> 1], 1u << ((l & 1) << 4)); }
        if ((v.z >> RANGE_BITS) == r) { int l = v.z & (RANGE - 1); atomicAdd(&cnt[l >> 1], 1u << ((l & 1) << 4)); }
        if ((v.w >> RANGE_BITS) == r) { int l = v.w & (RANGE - 1); atomicAdd(&cnt[l >> 1], 1u << ((l & 1) << 4)); }
    }
    for (; e < e1; ++e) {
        const int idx = arr[e];
        if ((idx >> RANGE_BITS) == r) { int l = idx & (RANGE - 1); atomicAdd(&cnt[l >> 1], 1u << ((l & 1) << 4)); }
    }
    __syncthreads();
    for (int i = threadIdx.x; i < RANGE / 2; i += 256) part[i] = cnt[i];
}

// ---------------- reduce partials -> degrees/norms; dst partials -> slice prefixes ----------------
__global__ __launch_bounds__(256) void k_deg_reduce(unsigned int* __restrict__ pS,
                                                    unsigned int* __restrict__ pD,
                                                    float* __restrict__ out_norm,
                                                    float* __restrict__ in_norm,
                                                    int* __restrict__ in_deg, int N) {
    const int a = blockIdx.y;
    const int t = blockIdx.x * 256 + threadIdx.x;
    const int r = t >> (RANGE_BITS - 1);
    const int w = t & ((RANGE / 2) - 1);
    unsigned int* base = (a ? pD : pS) + (size_t)r * NSLICE * (RANGE / 2) + w;
    unsigned int lo = 0, hi = 0;
    if (a) {
        for (int s = 0; s < NSLICE; ++s) {
            const unsigned int v = base[(size_t)s * (RANGE / 2)];
            base[(size_t)s * (RANGE / 2)] = lo | (hi << 16);
            lo += v & 0xffffu; hi += v >> 16;
        }
    } else {
        for (int s = 0; s < NSLICE; ++s) {
            const unsigned int v = base[(size_t)s * (RANGE / 2)];
            lo += v & 0xffffu; hi += v >> 16;
        }
    }
    const int n0 = r * RANGE + 2 * w, n1 = n0 + 1;
    if (a) {
        if (n0 < N) { in_deg[n0] = (int)lo; in_norm[n0] = rsqrtf(fmaxf((float)lo, 1.f)); }
        if (n1 < N) { in_deg[n1] = (int)hi; in_norm[n1] = rsqrtf(fmaxf((float)hi, 1.f)); }
    } else {
        if (n0 < N) out_norm[n0] = rsqrtf(fmaxf((float)lo, 1.f));
        if (n1 < N) out_norm[n1] = rsqrtf(fmaxf((float)hi, 1.f));
    }
}

// ---------------- prefix-sum (3-phase) ----------------
__global__ __launch_bounds__(1024) void k_scan_block(const int* __restrict__ in,
                                                     int* __restrict__ row_ptr,
                                                     int* __restrict__ partials, int n) {
    __shared__ int sh[1024];
    int i = blockIdx.x * 1024 + threadIdx.x;
    int v = (i < n) ? in[i] : 0;
    sh[threadIdx.x] = v;
    __syncthreads();
    for (int off = 1; off < 1024; off <<= 1) {
        int t = (threadIdx.x >= off) ? sh[threadIdx.x - off] : 0;
        __syncthreads();
        sh[threadIdx.x] += t;
        __syncthreads();
    }
    if (i < n) row_ptr[i + 1] = sh[threadIdx.x];
    if (threadIdx.x == 1023) partials[blockIdx.x] = sh[1023];
}

__global__ __launch_bounds__(1024) void k_scan_partials(int* __restrict__ partials, int nb) {
    __shared__ int sh[1024];
    int v = (threadIdx.x < nb) ? partials[threadIdx.x] : 0;
    sh[threadIdx.x] = v;
    __syncthreads();
    for (int off = 1; off < 1024; off <<= 1) {
        int t = (threadIdx.x >= off) ? sh[threadIdx.x - off] : 0;
        __syncthreads();
        sh[threadIdx.x] += t;
        __syncthreads();
    }
    if (threadIdx.x < nb) partials[threadIdx.x] = sh[threadIdx.x] - v;
}

__global__ void k_scan_finalize(int* __restrict__ row_ptr, const int* __restrict__ partials,
                                int n) {
    int i = blockIdx.x * blockDim.x + threadIdx.x;
    if (i < n) {
        row_ptr[i + 1] += partials[i >> 10];
        if (i == 0) row_ptr[0] = 0;
    }
}

// ---------------- deterministic CSR scatter (no global atomics) ----------------
__global__ __launch_bounds__(256) void k_scatter_lds(const int* __restrict__ src,
                                                     const int* __restrict__ dst,
                                                     const unsigned int* __restrict__ pD,
                                                     const int* __restrict__ row_ptr,
                                                     int* __restrict__ ssrc, int E, int EPS) {
    __shared__ unsigned int cur[RANGE / 2];   // 32 KB
    const int r = blockIdx.x & 7;
    const int s = blockIdx.x >> 3;
    const unsigned int* pre = pD + ((size_t)r * NSLICE + s) * (RANGE / 2);
    for (int i = threadIdx.x; i < RANGE / 2; i += 256) cur[i] = pre[i];
    __syncthreads();
    const int e0 = s * EPS;
    const int e1 = min(E, e0 + EPS);
    int e = e0 + threadIdx.x * 4;
    for (; e + 3 < e1; e += 1024) {
        const int4 v = *(const int4*)&dst[e];
#pragma unroll
        for (int j = 0; j < 4; ++j) {
            const int d = (&v.x)[j];
            if ((d >> RANGE_BITS) == r) {
                const int local = d & (RANGE - 1);
                const int sh = (local & 1) << 4;
                const unsigned int old = atomicAdd(&cur[local >> 1], 1u << sh);
                const unsigned int off = (old >> sh) & 0xffffu;
                ssrc[row_ptr[d] + (int)off] = src[e + j];
            }
        }
    }
    for (; e < e1; ++e) {
        const int d = dst[e];
        if ((d >> RANGE_BITS) == r) {
            const int local = d & (RANGE - 1);
            const int sh = (local & 1) << 4;
            const unsigned int old = atomicAdd(&cur[local >> 1], 1u << sh);
            const unsigned int off = (old >> sh) & 0xffffu;
            ssrc[row_ptr[d] + (int)off] = src[e];
        }
    }
}

// ---------------- MFMA GEMM: out0[N,128](fp8) = rowscale(X @ W0); out1[N,128](bf16) = X @ W1 ----
// out_norm is folded into the stored gather table (values sigma ~0.2) -> fp8 e4m3
// needs no per-row scale. out1 (residual) stays bf16 for final-output precision.
template <typename TIN, int NW>
__global__ __launch_bounds__(256) void gemm_mfma(const TIN* __restrict__ X,
                                                 const unsigned short* __restrict__ Wt0,
                                                 const unsigned short* __restrict__ Wt1,
                                                 const float* __restrict__ scale,
                                                 unsigned char* __restrict__ out0,
                                                 unsigned short* __restrict__ out1,
                                                 int N) {
    __shared__ unsigned short Ws[NW][128 * 128];   // 32 KB per weight (64 KB max)
    const int tid = threadIdx.x;
#pragma unroll
    for (int w = 0; w < NW; ++w) {
        const unsigned short* Wsrc = w ? Wt1 : Wt0;
        for (int i = tid; i < 2048; i += 256) {
            const int n = i >> 4, b = i & 15;
            const uint4 v = *(const uint4*)&Wsrc[(size_t)n * 128 + b * 8];
            *(uint4*)&Ws[w][n * 128 + ((b ^ (n & 15)) << 3)] = v;
        }
    }
    __syncthreads();

    const int lane = tid & 63;
    const int wave = tid >> 6;
    const int quad = lane >> 4;
    const int l16 = lane & 15;
    const int r_base = blockIdx.x * 64 + wave * 16;
    const int ra = min(r_base + l16, N - 1);          // A-operand row (clamped)

    f4v acc[NW][8];
#pragma unroll
    for (int w = 0; w < NW; ++w)
#pragma unroll
        for (int nn = 0; nn < 8; ++nn) acc[w][nn] = (f4v)0.f;

    const TIN* xp = X + (size_t)ra * 128 + quad * 8;

#pragma unroll
    for (int kt = 0; kt < 4; ++kt) {
        s8v af;
        if constexpr (sizeof(TIN) == 4) {
            const float4 lo = *(const float4*)(xp + kt * 32);
            const float4 hi = *(const float4*)(xp + kt * 32 + 4);
            af[0] = (short)f2bf(lo.x); af[1] = (short)f2bf(lo.y);
            af[2] = (short)f2bf(lo.z); af[3] = (short)f2bf(lo.w);
            af[4] = (short)f2bf(hi.x); af[5] = (short)f2bf(hi.y);
            af[6] = (short)f2bf(hi.z); af[7] = (short)f2bf(hi.w);
        } else {
            af = *(const s8v*)(xp + kt * 32);
        }
#pragma unroll
        for (int nn = 0; nn < 8; ++nn) {
            const int bofs = (nn * 16 + l16) * 128 + (((kt * 4 + quad) ^ l16) << 3);
#pragma unroll
            for (int w = 0; w < NW; ++w) {
                const s8v bf = *(const s8v*)&Ws[w][bofs];
                acc[w][nn] = mfma16(af, bf, acc[w][nn]);
            }
        }
    }

    // epilogue: C/D layout col = lane&15, row = quad*4 + reg
    const int rc = r_base + quad * 4;
    float sc[4];
#pragma unroll
    for (int g = 0; g < 4; ++g) sc[g] = scale[min(rc + g, N - 1)];
#pragma unroll
    for (int nn = 0; nn < 8; ++nn) {
        const int col = nn * 16 + l16;
#pragma unroll
        for (int g = 0; g < 4; ++g) {
            const int r = rc + g;
            if (r < N) {
                out0[(size_t)r * 128 + col] = f2fp8(acc[0][nn][g] * sc[g]);
                if constexpr (NW == 2)
                    out1[(size_t)r * 128 + col] = (unsigned short)f2bf(acc[1][nn][g]);
            }
        }
    }
}

// ---------------- CSR aggregation (one wave per dst node, fp8 gather table) ----
// 16-lane group per edge, uint2 (8B = 8 fp8) per lane; HW cvt_pk_f32_fp8 dequant.
template <int FINAL>
__global__ __launch_bounds__(256) void spmm_agg(const unsigned char* __restrict__ T,
                                                const int* __restrict__ row_ptr,
                                                const int* __restrict__ ssrc,
                                                const float* __restrict__ in_norm,
                                                const float* __restrict__ bias,
                                                unsigned short* __restrict__ Hout,
                                                const unsigned short* __restrict__ Res,
                                                const float* __restrict__ mlpW,
                                                const float* __restrict__ mlpB,
                                                float* __restrict__ out, int N) {
    const int lane = threadIdx.x & 63;
    const int grp = lane >> 4;        // edge group 0..3
    const int gl  = lane & 15;        // 8B column chunk within fp8 row
    const int d = blockIdx.x * 4 + (threadIdx.x >> 6);
    if (d >= N) return;

    const int start = row_ptr[d], end = row_ptr[d + 1];
    float acc[8];
#pragma unroll
    for (int j = 0; j < 8; ++j) acc[j] = 0.f;

    for (int base = start; base < end; base += 64) {
        const int cnt = min(64, end - base);
        const int sl = (lane < cnt) ? ssrc[base + lane] : 0;
        for (int i = 0; i < cnt; i += 8) {
            const int e0 = i + grp, e1 = i + 4 + grp;
            const int s0 = __shfl(sl, min(e0, cnt - 1));
            const int s1 = __shfl(sl, min(e1, cnt - 1));
            const uint2 w0 = *(const uint2*)&T[(size_t)s0 * 128 + gl * 8];
            const uint2 w1 = *(const uint2*)&T[(size_t)s1 * 128 + gl * 8];
            const float m0 = (e0 < cnt) ? 1.f : 0.f;
            const float m1 = (e1 < cnt) ? 1.f : 0.f;
            const f2v a0 = __builtin_amdgcn_cvt_pk_f32_fp8(w0.x, false);
            const f2v a1 = __builtin_amdgcn_cvt_pk_f32_fp8(w0.x, true);
            const f2v a2 = __builtin_amdgcn_cvt_pk_f32_fp8(w0.y, false);
            const f2v a3 = __builtin_amdgcn_cvt_pk_f32_fp8(w0.y, true);
            acc[0] = fmaf(m0, a0[0], acc[0]); acc[1] = fmaf(m0, a0[1], acc[1]);
            acc[2] = fmaf(m0, a1[0], acc[2]); acc[3] = fmaf(m0, a1[1], acc[3]);
            acc[4] = fmaf(m0, a2[0], acc[4]); acc[5] = fmaf(m0, a2[1], acc[5]);
            acc[6] = fmaf(m0, a3[0], acc[6]); acc[7] = fmaf(m0, a3[1], acc[7]);
            const f2v b0 = __builtin_amdgcn_cvt_pk_f32_fp8(w1.x, false);
            const f2v b1 = __builtin_amdgcn_cvt_pk_f32_fp8(w1.x, true);
            const f2v b2 = __builtin_amdgcn_cvt_pk_f32_fp8(w1.y, false);
            const f2v b3 = __builtin_amdgcn_cvt_pk_f32_fp8(w1.y, true);
            acc[0] = fmaf(m1, b0[0], acc[0]); acc[1] = fmaf(m1, b0[1], acc[1]);
            acc[2] = fmaf(m1, b1[0], acc[2]); acc[3] = fmaf(m1, b1[1], acc[3]);
            acc[4] = fmaf(m1, b2[0], acc[4]); acc[5] = fmaf(m1, b2[1], acc[5]);
            acc[6] = fmaf(m1, b3[0], acc[6]); acc[7] = fmaf(m1, b3[1], acc[7]);
        }
    }

    // sum the 4 edge-groups (same columns, different edges)
#pragma unroll
    for (int j = 0; j < 8; ++j) {
        acc[j] += __shfl_xor(acc[j], 16);
        acc[j] += __shfl_xor(acc[j], 32);
    }

    const float inr = in_norm[d];
    const float4 bb0 = *(const float4*)&bias[gl * 8];
    const float4 bb1 = *(const float4*)&bias[gl * 8 + 4];
    float v[8];
    v[0] = acc[0] * inr + bb0.x; v[1] = acc[1] * inr + bb0.y;
    v[2] = acc[2] * inr + bb0.z; v[3] = acc[3] * inr + bb0.w;
    v[4] = acc[4] * inr + bb1.x; v[5] = acc[5] * inr + bb1.y;
    v[6] = acc[6] * inr + bb1.z; v[7] = acc[7] * inr + bb1.w;

    if constexpr (FINAL == 0) {
#pragma unroll
        for (int j = 0; j < 8; ++j) v[j] = fmaxf(v[j], 0.f);
        if (grp == 0) {
            uint4 o;
            o.x = packbf(v[0], v[1]); o.y = packbf(v[2], v[3]);
            o.z = packbf(v[4], v[5]); o.w = packbf(v[6], v[7]);
            *(uint4*)&Hout[(size_t)d * 128 + gl * 8] = o;
        }
    } else {
        const uint4 rw = *(const uint4*)&Res[(size_t)d * 128 + gl * 8];
        v[0] += bflo(rw.x); v[1] += bfhi(rw.x);
        v[2] += bflo(rw.y); v[3] += bfhi(rw.y);
        v[4] += bflo(rw.z); v[5] += bfhi(rw.z);
        v[6] += bflo(rw.w); v[7] += bfhi(rw.w);
        // mlpW rows gl*8..gl*8+7, 2 floats each = 4 float4
        const float4* mwp = (const float4*)&mlpW[gl * 16];
        float p0 = 0.f, p1 = 0.f;
#pragma unroll
        for (int q = 0; q < 4; ++q) {
            const float4 mw = mwp[q];
            p0 = fmaf(v[2 * q], mw.x, p0);     p1 = fmaf(v[2 * q], mw.y, p1);
            p0 = fmaf(v[2 * q + 1], mw.z, p0); p1 = fmaf(v[2 * q + 1], mw.w, p1);
        }
#pragma unroll
        for (int off = 8; off > 0; off >>= 1) {
            p0 += __shfl_xor(p0, off);
            p1 += __shfl_xor(p1, off);
        }
        if (lane == 0) {
            out[(size_t)d * 2 + 0] = p0 + mlpB[0];
            out[(size_t)d * 2 + 1] = p1 + mlpB[1];
        }
    }
}

// ---------------- launch ----------------
extern "C" void kernel_launch(void* const* d_in, const int* in_sizes, int n_in,
                              void* d_out, int out_size, void* d_ws, size_t ws_size,
                              hipStream_t stream) {
    const float* x     = (const float*)d_in[0];
    const int*   src   = (const int*)d_in[1];
    const int*   dst   = (const int*)d_in[2];
    const float* W1    = (const float*)d_in[3];
    const float* b1    = (const float*)d_in[4];
    const float* W2    = (const float*)d_in[5];
    const float* b2    = (const float*)d_in[6];
    const float* res_W = (const float*)d_in[7];
    const float* mlp_W = (const float*)d_in[8];
    const float* mlp_b = (const float*)d_in[9];
    float* out = (float*)d_out;

    const int N = in_sizes[0] / 128;
    const int E = in_sizes[1];
    const int EPS = (E + NSLICE - 1) / NSLICE;

    // workspace layout. partialS aliases A+B head (dead before gemm1/spmm1 write
    // them), partialD aliases C (dead before gemm1 writes C).
    char* p = (char*)d_ws;
    unsigned char*  A = (unsigned char*)p;   p += (size_t)N * 128;       // t1 / t2 (fp8, 12.8 MB)
    unsigned short* B = (unsigned short*)p;  p += (size_t)N * 128 * 2;   // h1 (bf16)
    unsigned short* C = (unsigned short*)p;  p += (size_t)N * 128 * 2;   // res (bf16, aliases partialD)
    unsigned short* Wt = (unsigned short*)p; p += (size_t)3 * 16384 * 2; // Wt1|Wt2|Rt bf16
    float* out_norm = (float*)p;             p += (size_t)N * 4;
    float* in_norm  = (float*)p;             p += (size_t)N * 4;
    int* in_deg     = (int*)p;               p += (size_t)N * 4;
    int* row_ptr    = (int*)p;               p += (size_t)(N + 1) * 4;
    int* scanpart   = (int*)p;               p += (size_t)1024 * 4;
    int* ssrc       = (int*)p;               p += (size_t)E * 4;
    unsigned int* partialS = (unsigned int*)A;   // 16.8 MB <= A(12.8)+B head
    unsigned int* partialD = (unsigned int*)C;   // 16.8 MB <= C(25.6)

    const int gN = (N + 255) / 256;
    const int nb = (N + 1023) / 1024;
    const int gGemm = (N + 63) / 64;
    const int gSpmm = (N + 3) / 4;

    // 0. weights -> transposed bf16
    k_prep_w<<<dim3(3, 4), 256, 0, stream>>>(W1, W2, res_W, Wt);

    // 1. degrees + norms + slice prefixes (no global atomics)
    k_hist_lds<<<dim3(NR_PAD * NSLICE, 2), 256, 0, stream>>>(src, dst, partialS, partialD, E, EPS);
    k_deg_reduce<<<dim3(NR_PAD * (RANGE / 2) / 256, 2), 256, 0, stream>>>(partialS, partialD,
                                                                          out_norm, in_norm, in_deg, N);

    // 2. row_ptr scan + deterministic CSR scatter
    k_scan_block<<<nb, 1024, 0, stream>>>(in_deg, row_ptr, scanpart, N);
    k_scan_partials<<<1, 1024, 0, stream>>>(scanpart, nb);
    k_scan_finalize<<<gN, 256, 0, stream>>>(row_ptr, scanpart, N);
    k_scatter_lds<<<NR_PAD * NSLICE, 256, 0, stream>>>(src, dst, partialD, row_ptr, ssrc, E, EPS);

    // 3. fused gemm1+gemm3: A(fp8) = rowscale(x@W1, out_norm), C(bf16) = x@res_W
    gemm_mfma<float, 2><<<gGemm, 256, 0, stream>>>(x, Wt, Wt + 2 * 16384, out_norm, A, C, N);

    // 4. layer-1 aggregation: B = relu(agg(A)*in_norm + b1)
    spmm_agg<0><<<gSpmm, 256, 0, stream>>>(A, row_ptr, ssrc, in_norm, b1, B,
                                           (const unsigned short*)nullptr, nullptr, nullptr,
                                           nullptr, N);

    // 5. gemm2: A(fp8) = rowscale(B@W2, out_norm)
    gemm_mfma<unsigned short, 1><<<gGemm, 256, 0, stream>>>(B, Wt + 16384, nullptr,
                                                            out_norm, A, nullptr, N);

    // 6. final aggregation + residual + MLP head -> out
    spmm_agg<1><<<gSpmm, 256, 0, stream>>>(A, row_ptr, ssrc, in_norm, b2, nullptr,
                                           C, mlp_W, mlp_b, out, N);

    (void)n_in; (void)out_size; (void)ws_size;
}

// Round 10
// 332.846 us; speedup vs baseline: 7.7891x; 1.0031x over previous
//
#include <hip/hip_runtime.h>
#include <stdint.h>

// ---------------- bf16 helpers (raw ushort storage) ----------------
__device__ __forceinline__ float bflo(unsigned int u) {
    union { unsigned int u; float f; } c; c.u = u << 16; return c.f;
}
__device__ __forceinline__ float bfhi(unsigned int u) {
    union { unsigned int u; float f; } c; c.u = u & 0xffff0000u; return c.f;
}
__device__ __forceinline__ unsigned int f2bf(float f) {
    union { float f; unsigned int u; } c; c.f = f;
    unsigned int u = c.u;
    u += 0x7fffu + ((u >> 16) & 1u);   // round-to-nearest-even
    return u >> 16;
}
__device__ __forceinline__ unsigned int packbf(float a, float b) {
    return f2bf(a) | (f2bf(b) << 16);
}

typedef __attribute__((ext_vector_type(8))) short s8v;   // 8 bf16 (4 VGPRs)
typedef __attribute__((ext_vector_type(4))) float f4v;   // MFMA accumulator
typedef __attribute__((ext_vector_type(2))) float f2v;   // fp8 unpack pair

__device__ __forceinline__ f4v mfma16(s8v a, s8v b, f4v c) {
    return __builtin_amdgcn_mfma_f32_16x16x32_bf16(a, b, c, 0, 0, 0);
}

// fp8 e4m3 (OCP) pack via gfx950 HW converter
__device__ __forceinline__ unsigned char f2fp8(float v) {
    return (unsigned char)(__builtin_amdgcn_cvt_pk_fp8_f32(v, v, 0, false) & 0xff);
}

// ---------------- counting-sort parameters ----------------
#define RANGE_BITS 14
#define RANGE (1 << RANGE_BITS)     // 16384 nodes per LDS range (32 KB @ 2B/node)
#define NR_PAD 8                    // ranges padded to 8 for XCD swizzle (range = bid & 7)
#define NSLICE 64                   // edge slices; per-slice count <= E/64 = 25000 < 2^16

// ---------------- weight prep: W[k][n] f32 -> Wt[n][k] bf16 ----------------
__global__ __launch_bounds__(256) void k_prep_w(const float* __restrict__ W1,
                                                const float* __restrict__ W2,
                                                const float* __restrict__ Wr,
                                                unsigned short* __restrict__ Wt) {
    const float* W = (blockIdx.x == 0) ? W1 : (blockIdx.x == 1) ? W2 : Wr;
    unsigned short* T = Wt + (size_t)blockIdx.x * 16384;
    const int wv = threadIdx.x >> 6, l = threadIdx.x & 63;
    const int kb = blockIdx.y * 32 + wv * 8;
#pragma unroll
    for (int half = 0; half < 2; ++half) {
        const int n = l + half * 64;
        unsigned short tmp[8];
#pragma unroll
        for (int j = 0; j < 8; ++j) tmp[j] = (unsigned short)f2bf(W[(size_t)(kb + j) * 128 + n]);
#pragma unroll
        for (int j = 0; j < 8; j += 2)
            *(unsigned int*)&T[(size_t)n * 128 + kb + j] =
                (unsigned int)tmp[j] | ((unsigned int)tmp[j + 1] << 16);
    }
}

// ---------------- LDS-privatized degree histogram (no global atomics) ----------------
__global__ __launch_bounds__(256) void k_hist_lds(const int* __restrict__ src,
                                                  const int* __restrict__ dst,
                                                  unsigned int* __restrict__ partialS,
                                                  unsigned int* __restrict__ partialD,
                                                  int E, int EPS) {
    __shared__ unsigned int cnt[RANGE / 2];   // 32 KB
    const int r = blockIdx.x & 7;
    const int s = blockIdx.x >> 3;
    const int a = blockIdx.y;
    const int* __restrict__ arr = a ? dst : src;
    unsigned int* part = (a ? partialD : partialS)
                         + ((size_t)r * NSLICE + s) * (RANGE / 2);
    for (int i = threadIdx.x; i < RANGE / 2; i += 256) cnt[i] = 0;
    __syncthreads();
    const int e0 = s * EPS;
    const int e1 = min(E, e0 + EPS);
    int e = e0 + threadIdx.x * 4;
    for (; e + 3 < e1; e += 1024) {
        const int4 v = *(const int4*)&arr[e];
        if ((v.x >> RANGE_BITS) == r) { int l = v.x & (RANGE - 1); atomicAdd(&cnt[l >> 1], 1u << ((l & 1) << 4)); }
        if ((v.y >> RANGE_BITS) == r) { int l = v.y & (RANGE - 1); atomicAdd(&cnt[l >> 1], 1u << ((l & 1) << 4)); }
        if ((v.z >> RANGE_BITS) == r) { int l = v.z & (RANGE - 1); atomicAdd(&cnt[l >> 1], 1u << ((l & 1) << 4)); }
        if ((v.w >> RANGE_BITS) == r) { int l = v.w & (RANGE - 1); atomicAdd(&cnt[l >> 1], 1u << ((l & 1) << 4)); }
    }
    for (; e < e1; ++e) {
        const int idx = arr[e];
        if ((idx >> RANGE_BITS) == r) { int l = idx & (RANGE - 1); atomicAdd(&cnt[l >> 1], 1u << ((l & 1) << 4)); }
    }
    __syncthreads();
    for (int i = threadIdx.x; i < RANGE / 2; i += 256) part[i] = cnt[i];
}

// ---------------- reduce partials -> degrees/norms; dst partials -> slice prefixes ----------------
__global__ __launch_bounds__(256) void k_deg_reduce(unsigned int* __restrict__ pS,
                                                    unsigned int* __restrict__ pD,
                                                    float* __restrict__ out_norm,
                                                    float* __restrict__ in_norm,
                                                    int* __restrict__ in_deg, int N) {
    const int a = blockIdx.y;
    const int t = blockIdx.x * 256 + threadIdx.x;
    const int r = t >> (RANGE_BITS - 1);
    const int w = t & ((RANGE / 2) - 1);
    unsigned int* base = (a ? pD : pS) + (size_t)r * NSLICE * (RANGE / 2) + w;
    unsigned int lo = 0, hi = 0;
    if (a) {
        for (int s = 0; s < NSLICE; ++s) {
            const unsigned int v = base[(size_t)s * (RANGE / 2)];
            base[(size_t)s * (RANGE / 2)] = lo | (hi << 16);
            lo += v & 0xffffu; hi += v >> 16;
        }
    } else {
        for (int s = 0; s < NSLICE; ++s) {
            const unsigned int v = base[(size_t)s * (RANGE / 2)];
            lo += v & 0xffffu; hi += v >> 16;
        }
    }
    const int n0 = r * RANGE + 2 * w, n1 = n0 + 1;
    if (a) {
        if (n0 < N) { in_deg[n0] = (int)lo; in_norm[n0] = rsqrtf(fmaxf((float)lo, 1.f)); }
        if (n1 < N) { in_deg[n1] = (int)hi; in_norm[n1] = rsqrtf(fmaxf((float)hi, 1.f)); }
    } else {
        if (n0 < N) out_norm[n0] = rsqrtf(fmaxf((float)lo, 1.f));
        if (n1 < N) out_norm[n1] = rsqrtf(fmaxf((float)hi, 1.f));
    }
}

// ---------------- prefix-sum (3-phase) ----------------
__global__ __launch_bounds__(1024) void k_scan_block(const int* __restrict__ in,
                                                     int* __restrict__ row_ptr,
                                                     int* __restrict__ partials, int n) {
    __shared__ int sh[1024];
    int i = blockIdx.x * 1024 + threadIdx.x;
    int v = (i < n) ? in[i] : 0;
    sh[threadIdx.x] = v;
    __syncthreads();
    for (int off = 1; off < 1024; off <<= 1) {
        int t = (threadIdx.x >= off) ? sh[threadIdx.x - off] : 0;
        __syncthreads();
        sh[threadIdx.x] += t;
        __syncthreads();
    }
    if (i < n) row_ptr[i + 1] = sh[threadIdx.x];
    if (threadIdx.x == 1023) partials[blockIdx.x] = sh[1023];
}

__global__ __launch_bounds__(1024) void k_scan_partials(int* __restrict__ partials, int nb) {
    __shared__ int sh[1024];
    int v = (threadIdx.x < nb) ? partials[threadIdx.x] : 0;
    sh[threadIdx.x] = v;
    __syncthreads();
    for (int off = 1; off < 1024; off <<= 1) {
        int t = (threadIdx.x >= off) ? sh[threadIdx.x - off] : 0;
        __syncthreads();
        sh[threadIdx.x] += t;
        __syncthreads();
    }
    if (threadIdx.x < nb) partials[threadIdx.x] = sh[threadIdx.x] - v;
}

__global__ void k_scan_finalize(int* __restrict__ row_ptr, const int* __restrict__ partials,
                                int n) {
    int i = blockIdx.x * blockDim.x + threadIdx.x;
    if (i < n) {
        row_ptr[i + 1] += partials[i >> 10];
        if (i == 0) row_ptr[0] = 0;
    }
}

// ---------------- deterministic CSR scatter (no global atomics) ----------------
__global__ __launch_bounds__(256) void k_scatter_lds(const int* __restrict__ src,
                                                     const int* __restrict__ dst,
                                                     const unsigned int* __restrict__ pD,
                                                     const int* __restrict__ row_ptr,
                                                     int* __restrict__ ssrc, int E, int EPS) {
    __shared__ unsigned int cur[RANGE / 2];   // 32 KB
    const int r = blockIdx.x & 7;
    const int s = blockIdx.x >> 3;
    const unsigned int* pre = pD + ((size_t)r * NSLICE + s) * (RANGE / 2);
    for (int i = threadIdx.x; i < RANGE / 2; i += 256) cur[i] = pre[i];
    __syncthreads();
    const int e0 = s * EPS;
    const int e1 = min(E, e0 + EPS);
    int e = e0 + threadIdx.x * 4;
    for (; e + 3 < e1; e += 1024) {
        const int4 v = *(const int4*)&dst[e];
#pragma unroll
        for (int j = 0; j < 4; ++j) {
            const int d = (&v.x)[j];
            if ((d >> RANGE_BITS) == r) {
                const int local = d & (RANGE - 1);
                const int sh = (local & 1) << 4;
                const unsigned int old = atomicAdd(&cur[local >> 1], 1u << sh);
                const unsigned int off = (old >> sh) & 0xffffu;
                ssrc[row_ptr[d] + (int)off] = src[e + j];
            }
        }
    }
    for (; e < e1; ++e) {
        const int d = dst[e];
        if ((d >> RANGE_BITS) == r) {
            const int local = d & (RANGE - 1);
            const int sh = (local & 1) << 4;
            const unsigned int old = atomicAdd(&cur[local >> 1], 1u << sh);
            const unsigned int off = (old >> sh) & 0xffffu;
            ssrc[row_ptr[d] + (int)off] = src[e];
        }
    }
}

// ---------------- MFMA GEMM: out0[N,128](fp8) = rowscale(X @ W0); out1[N,128](bf16) = X @ W1 ----
template <typename TIN, int NW>
__global__ __launch_bounds__(256) void gemm_mfma(const TIN* __restrict__ X,
                                                 const unsigned short* __restrict__ Wt0,
                                                 const unsigned short* __restrict__ Wt1,
                                                 const float* __restrict__ scale,
                                                 unsigned char* __restrict__ out0,
                                                 unsigned short* __restrict__ out1,
                                                 int N) {
    __shared__ unsigned short Ws[NW][128 * 128];   // 32 KB per weight (64 KB max)
    const int tid = threadIdx.x;
#pragma unroll
    for (int w = 0; w < NW; ++w) {
        const unsigned short* Wsrc = w ? Wt1 : Wt0;
        for (int i = tid; i < 2048; i += 256) {
            const int n = i >> 4, b = i & 15;
            const uint4 v = *(const uint4*)&Wsrc[(size_t)n * 128 + b * 8];
            *(uint4*)&Ws[w][n * 128 + ((b ^ (n & 15)) << 3)] = v;
        }
    }
    __syncthreads();

    const int lane = tid & 63;
    const int wave = tid >> 6;
    const int quad = lane >> 4;
    const int l16 = lane & 15;
    const int r_base = blockIdx.x * 64 + wave * 16;
    const int ra = min(r_base + l16, N - 1);          // A-operand row (clamped)

    f4v acc[NW][8];
#pragma unroll
    for (int w = 0; w < NW; ++w)
#pragma unroll
        for (int nn = 0; nn < 8; ++nn) acc[w][nn] = (f4v)0.f;

    const TIN* xp = X + (size_t)ra * 128 + quad * 8;

#pragma unroll
    for (int kt = 0; kt < 4; ++kt) {
        s8v af;
        if constexpr (sizeof(TIN) == 4) {
            const float4 lo = *(const float4*)(xp + kt * 32);
            const float4 hi = *(const float4*)(xp + kt * 32 + 4);
            af[0] = (short)f2bf(lo.x); af[1] = (short)f2bf(lo.y);
            af[2] = (short)f2bf(lo.z); af[3] = (short)f2bf(lo.w);
            af[4] = (short)f2bf(hi.x); af[5] = (short)f2bf(hi.y);
            af[6] = (short)f2bf(hi.z); af[7] = (short)f2bf(hi.w);
        } else {
            af = *(const s8v*)(xp + kt * 32);
        }
#pragma unroll
        for (int nn = 0; nn < 8; ++nn) {
            const int bofs = (nn * 16 + l16) * 128 + (((kt * 4 + quad) ^ l16) << 3);
#pragma unroll
            for (int w = 0; w < NW; ++w) {
                const s8v bf = *(const s8v*)&Ws[w][bofs];
                acc[w][nn] = mfma16(af, bf, acc[w][nn]);
            }
        }
    }

    // epilogue: C/D layout col = lane&15, row = quad*4 + reg
    const int rc = r_base + quad * 4;
    float sc[4];
#pragma unroll
    for (int g = 0; g < 4; ++g) sc[g] = scale[min(rc + g, N - 1)];
#pragma unroll
    for (int nn = 0; nn < 8; ++nn) {
        const int col = nn * 16 + l16;
#pragma unroll
        for (int g = 0; g < 4; ++g) {
            const int r = rc + g;
            if (r < N) {
                out0[(size_t)r * 128 + col] = f2fp8(acc[0][nn][g] * sc[g]);
                if constexpr (NW == 2)
                    out1[(size_t)r * 128 + col] = (unsigned short)f2bf(acc[1][nn][g]);
            }
        }
    }
}

// ---------------- CSR aggregation (one wave per dst node, fp8 gather table) ----
// 16-lane group per edge, uint2 (8B = 8 fp8) per lane. MLP-widened: 16 edges
// per iteration = 4 independent gather loads in flight before any accumulate.
// (Same experiment as the two infra-failed rounds, re-expressed as unroll
// loops over arrays instead of hand-expanded blocks.)
template <int FINAL>
__global__ __launch_bounds__(256) void spmm_agg(const unsigned char* __restrict__ T,
                                                const int* __restrict__ row_ptr,
                                                const int* __restrict__ ssrc,
                                                const float* __restrict__ in_norm,
                                                const float* __restrict__ bias,
                                                unsigned short* __restrict__ Hout,
                                                const unsigned short* __restrict__ Res,
                                                const float* __restrict__ mlpW,
                                                const float* __restrict__ mlpB,
                                                float* __restrict__ out, int N) {
    const int lane = threadIdx.x & 63;
    const int grp = lane >> 4;        // edge group 0..3
    const int gl  = lane & 15;        // 8B column chunk within fp8 row
    const int d = blockIdx.x * 4 + (threadIdx.x >> 6);
    if (d >= N) return;

    const int start = row_ptr[d], end = row_ptr[d + 1];
    float acc[8];
#pragma unroll
    for (int j = 0; j < 8; ++j) acc[j] = 0.f;

    for (int base = start; base < end; base += 64) {
        const int cnt = min(64, end - base);
        const int sl = (lane < cnt) ? ssrc[base + lane] : 0;
        for (int i = 0; i < cnt; i += 16) {
            int   ss[4];
            float mm[4];
            uint2 ww[4];
#pragma unroll
            for (int u = 0; u < 4; ++u) {
                const int e = i + 4 * u + grp;
                ss[u] = __shfl(sl, min(e, cnt - 1));
                mm[u] = (e < cnt) ? 1.f : 0.f;
            }
#pragma unroll
            for (int u = 0; u < 4; ++u)
                ww[u] = *(const uint2*)&T[(size_t)ss[u] * 128 + gl * 8];
#pragma unroll
            for (int u = 0; u < 4; ++u) {
                const f2v a0 = __builtin_amdgcn_cvt_pk_f32_fp8(ww[u].x, false);
                const f2v a1 = __builtin_amdgcn_cvt_pk_f32_fp8(ww[u].x, true);
                const f2v a2 = __builtin_amdgcn_cvt_pk_f32_fp8(ww[u].y, false);
                const f2v a3 = __builtin_amdgcn_cvt_pk_f32_fp8(ww[u].y, true);
                const float m = mm[u];
                acc[0] = fmaf(m, a0[0], acc[0]); acc[1] = fmaf(m, a0[1], acc[1]);
                acc[2] = fmaf(m, a1[0], acc[2]); acc[3] = fmaf(m, a1[1], acc[3]);
                acc[4] = fmaf(m, a2[0], acc[4]); acc[5] = fmaf(m, a2[1], acc[5]);
                acc[6] = fmaf(m, a3[0], acc[6]); acc[7] = fmaf(m, a3[1], acc[7]);
            }
        }
    }

    // sum the 4 edge-groups (same columns, different edges)
#pragma unroll
    for (int j = 0; j < 8; ++j) {
        acc[j] += __shfl_xor(acc[j], 16);
        acc[j] += __shfl_xor(acc[j], 32);
    }

    const float inr = in_norm[d];
    const float4 bb0 = *(const float4*)&bias[gl * 8];
    const float4 bb1 = *(const float4*)&bias[gl * 8 + 4];
    float v[8];
    v[0] = acc[0] * inr + bb0.x; v[1] = acc[1] * inr + bb0.y;
    v[2] = acc[2] * inr + bb0.z; v[3] = acc[3] * inr + bb0.w;
    v[4] = acc[4] * inr + bb1.x; v[5] = acc[5] * inr + bb1.y;
    v[6] = acc[6] * inr + bb1.z; v[7] = acc[7] * inr + bb1.w;

    if constexpr (FINAL == 0) {
#pragma unroll
        for (int j = 0; j < 8; ++j) v[j] = fmaxf(v[j], 0.f);
        if (grp == 0) {
            uint4 o;
            o.x = packbf(v[0], v[1]); o.y = packbf(v[2], v[3]);
            o.z = packbf(v[4], v[5]); o.w = packbf(v[6], v[7]);
            *(uint4*)&Hout[(size_t)d * 128 + gl * 8] = o;
        }
    } else {
        const uint4 rw = *(const uint4*)&Res[(size_t)d * 128 + gl * 8];
        v[0] += bflo(rw.x); v[1] += bfhi(rw.x);
        v[2] += bflo(rw.y); v[3] += bfhi(rw.y);
        v[4] += bflo(rw.z); v[5] += bfhi(rw.z);
        v[6] += bflo(rw.w); v[7] += bfhi(rw.w);
        // mlpW rows gl*8..gl*8+7, 2 floats each = 4 float4
        const float4* mwp = (const float4*)&mlpW[gl * 16];
        float p0 = 0.f, p1 = 0.f;
#pragma unroll
        for (int q = 0; q < 4; ++q) {
            const float4 mw = mwp[q];
            p0 = fmaf(v[2 * q], mw.x, p0);     p1 = fmaf(v[2 * q], mw.y, p1);
            p0 = fmaf(v[2 * q + 1], mw.z, p0); p1 = fmaf(v[2 * q + 1], mw.w, p1);
        }
#pragma unroll
        for (int off = 8; off > 0; off >>= 1) {
            p0 += __shfl_xor(p0, off);
            p1 += __shfl_xor(p1, off);
        }
        if (lane == 0) {
            out[(size_t)d * 2 + 0] = p0 + mlpB[0];
            out[(size_t)d * 2 + 1] = p1 + mlpB[1];
        }
    }
}

// ---------------- launch ----------------
extern "C" void kernel_launch(void* const* d_in, const int* in_sizes, int n_in,
                              void* d_out, int out_size, void* d_ws, size_t ws_size,
                              hipStream_t stream) {
    const float* x     = (const float*)d_in[0];
    const int*   src   = (const int*)d_in[1];
    const int*   dst   = (const int*)d_in[2];
    const float* W1    = (const float*)d_in[3];
    const float* b1    = (const float*)d_in[4];
    const float* W2    = (const float*)d_in[5];
    const float* b2    = (const float*)d_in[6];
    const float* res_W = (const float*)d_in[7];
    const float* mlp_W = (const float*)d_in[8];
    const float* mlp_b = (const float*)d_in[9];
    float* out = (float*)d_out;

    const int N = in_sizes[0] / 128;
    const int E = in_sizes[1];
    const int EPS = (E + NSLICE - 1) / NSLICE;

    // workspace layout. partialS aliases A+B head (dead before gemm1/spmm1 write
    // them), partialD aliases C (dead before gemm1 writes C).
    char* p = (char*)d_ws;
    unsigned char*  A = (unsigned char*)p;   p += (size_t)N * 128;       // t1 / t2 (fp8, 12.8 MB)
    unsigned short* B = (unsigned short*)p;  p += (size_t)N * 128 * 2;   // h1 (bf16)
    unsigned short* C = (unsigned short*)p;  p += (size_t)N * 128 * 2;   // res (bf16, aliases partialD)
    unsigned short* Wt = (unsigned short*)p; p += (size_t)3 * 16384 * 2; // Wt1|Wt2|Rt bf16
    float* out_norm = (float*)p;             p += (size_t)N * 4;
    float* in_norm  = (float*)p;             p += (size_t)N * 4;
    int* in_deg     = (int*)p;               p += (size_t)N * 4;
    int* row_ptr    = (int*)p;               p += (size_t)(N + 1) * 4;
    int* scanpart   = (int*)p;               p += (size_t)1024 * 4;
    int* ssrc       = (int*)p;               p += (size_t)E * 4;
    unsigned int* partialS = (unsigned int*)A;   // 16.8 MB <= A(12.8)+B head
    unsigned int* partialD = (unsigned int*)C;   // 16.8 MB <= C(25.6)

    const int gN = (N + 255) / 256;
    const int nb = (N + 1023) / 1024;
    const int gGemm = (N + 63) / 64;
    const int gSpmm = (N + 3) / 4;

    // 0. weights -> transposed bf16
    k_prep_w<<<dim3(3, 4), 256, 0, stream>>>(W1, W2, res_W, Wt);

    // 1. degrees + norms + slice prefixes (no global atomics)
    k_hist_lds<<<dim3(NR_PAD * NSLICE, 2), 256, 0, stream>>>(src, dst, partialS, partialD, E, EPS);
    k_deg_reduce<<<dim3(NR_PAD * (RANGE / 2) / 256, 2), 256, 0, stream>>>(partialS, partialD,
                                                                          out_norm, in_norm, in_deg, N);

    // 2. row_ptr scan + deterministic CSR scatter
    k_scan_block<<<nb, 1024, 0, stream>>>(in_deg, row_ptr, scanpart, N);
    k_scan_partials<<<1, 1024, 0, stream>>>(scanpart, nb);
    k_scan_finalize<<<gN, 256, 0, stream>>>(row_ptr, scanpart, N);
    k_scatter_lds<<<NR_PAD * NSLICE, 256, 0, stream>>>(src, dst, partialD, row_ptr, ssrc, E, EPS);

    // 3. fused gemm1+gemm3: A(fp8) = rowscale(x@W1, out_norm), C(bf16) = x@res_W
    gemm_mfma<float, 2><<<gGemm, 256, 0, stream>>>(x, Wt, Wt + 2 * 16384, out_norm, A, C, N);

    // 4. layer-1 aggregation: B = relu(agg(A)*in_norm + b1)
    spmm_agg<0><<<gSpmm, 256, 0, stream>>>(A, row_ptr, ssrc, in_norm, b1, B,
                                           (const unsigned short*)nullptr, nullptr, nullptr,
                                           nullptr, N);

    // 5. gemm2: A(fp8) = rowscale(B@W2, out_norm)
    gemm_mfma<unsigned short, 1><<<gGemm, 256, 0, stream>>>(B, Wt + 16384, nullptr,
                                                            out_norm, A, nullptr, N);

    // 6. final aggregation + residual + MLP head -> out
    spmm_agg<1><<<gSpmm, 256, 0, stream>>>(A, row_ptr, ssrc, in_norm, b2, nullptr,
                                           C, mlp_W, mlp_b, out, N);

    (void)n_in; (void)out_size; (void)ws_size;
}

// Round 12
// 289.006 us; speedup vs baseline: 8.9706x; 1.1517x over previous
//
#include <hip/hip_runtime.h>
#include <stdint.h>

// ---------------- bf16 helpers (raw ushort storage) ----------------
__device__ __forceinline__ float bflo(unsigned int u) {
    union { unsigned int u; float f; } c; c.u = u << 16; return c.f;
}
__device__ __forceinline__ float bfhi(unsigned int u) {
    union { unsigned int u; float f; } c; c.u = u & 0xffff0000u; return c.f;
}
__device__ __forceinline__ unsigned int f2bf(float f) {
    union { float f; unsigned int u; } c; c.f = f;
    unsigned int u = c.u;
    u += 0x7fffu + ((u >> 16) & 1u);   // round-to-nearest-even
    return u >> 16;
}
__device__ __forceinline__ unsigned int packbf(float a, float b) {
    return f2bf(a) | (f2bf(b) << 16);
}

typedef __attribute__((ext_vector_type(8))) short s8v;   // 8 bf16 (4 VGPRs)
typedef __attribute__((ext_vector_type(4))) float f4v;   // MFMA accumulator
typedef __attribute__((ext_vector_type(2))) float f2v;   // fp8 unpack pair

__device__ __forceinline__ f4v mfma16(s8v a, s8v b, f4v c) {
    return __builtin_amdgcn_mfma_f32_16x16x32_bf16(a, b, c, 0, 0, 0);
}

// fp8 e4m3 (OCP) pack via gfx950 HW converter
__device__ __forceinline__ unsigned char f2fp8(float v) {
    return (unsigned char)(__builtin_amdgcn_cvt_pk_fp8_f32(v, v, 0, false) & 0xff);
}

// ---------------- counting-sort parameters ----------------
#define RANGE_BITS 14
#define RANGE (1 << RANGE_BITS)     // 16384 nodes per LDS range (32 KB @ 2B/node)
#define NR_PAD 8                    // ranges padded to 8 for XCD swizzle (range = bid & 7)
#define NSLICE 64                   // edge slices; per-slice count <= E/64 = 25000 < 2^16

// ---------------- weight prep: W[k][n] f32 -> Wt[n][k] bf16 ----------------
__global__ __launch_bounds__(256) void k_prep_w(const float* __restrict__ W1,
                                                const float* __restrict__ W2,
                                                const float* __restrict__ Wr,
                                                unsigned short* __restrict__ Wt) {
    const float* W = (blockIdx.x == 0) ? W1 : (blockIdx.x == 1) ? W2 : Wr;
    unsigned short* T = Wt + (size_t)blockIdx.x * 16384;
    const int wv = threadIdx.x >> 6, l = threadIdx.x & 63;
    const int kb = blockIdx.y * 32 + wv * 8;
#pragma unroll
    for (int half = 0; half < 2; ++half) {
        const int n = l + half * 64;
        unsigned short tmp[8];
#pragma unroll
        for (int j = 0; j < 8; ++j) tmp[j] = (unsigned short)f2bf(W[(size_t)(kb + j) * 128 + n]);
#pragma unroll
        for (int j = 0; j < 8; j += 2)
            *(unsigned int*)&T[(size_t)n * 128 + kb + j] =
                (unsigned int)tmp[j] | ((unsigned int)tmp[j + 1] << 16);
    }
}

// ---------------- K = b2 @ mlpW + mlpB (2 floats) ----------------
__global__ __launch_bounds__(64) void k_prep_k(const float* __restrict__ b2,
                                               const float* __restrict__ mlpW,
                                               const float* __restrict__ mlpB,
                                               float* __restrict__ K) {
    const int l = threadIdx.x;
    float p0 = b2[l] * mlpW[l * 2 + 0] + b2[l + 64] * mlpW[(l + 64) * 2 + 0];
    float p1 = b2[l] * mlpW[l * 2 + 1] + b2[l + 64] * mlpW[(l + 64) * 2 + 1];
#pragma unroll
    for (int off = 32; off > 0; off >>= 1) {
        p0 += __shfl_xor(p0, off);
        p1 += __shfl_xor(p1, off);
    }
    if (l == 0) { K[0] = p0 + mlpB[0]; K[1] = p1 + mlpB[1]; }
}

// ---------------- LDS-privatized degree histogram (no global atomics) ----------------
__global__ __launch_bounds__(256) void k_hist_lds(const int* __restrict__ src,
                                                  const int* __restrict__ dst,
                                                  unsigned int* __restrict__ partialS,
                                                  unsigned int* __restrict__ partialD,
                                                  int E, int EPS) {
    __shared__ unsigned int cnt[RANGE / 2];   // 32 KB
    const int r = blockIdx.x & 7;
    const int s = blockIdx.x >> 3;
    const int a = blockIdx.y;
    const int* __restrict__ arr = a ? dst : src;
    unsigned int* part = (a ? partialD : partialS)
                         + ((size_t)r * NSLICE + s) * (RANGE / 2);
    for (int i = threadIdx.x; i < RANGE / 2; i += 256) cnt[i] = 0;
    __syncthreads();
    const int e0 = s * EPS;
    const int e1 = min(E, e0 + EPS);
    int e = e0 + threadIdx.x * 4;
    for (; e + 3 < e1; e += 1024) {
        const int4 v = *(const int4*)&arr[e];
        if ((v.x >> RANGE_BITS) == r) { int l = v.x & (RANGE - 1); atomicAdd(&cnt[l >> 1], 1u << ((l & 1) << 4)); }
        if ((v.y >> RANGE_BITS) == r) { int l = v.y & (RANGE - 1); atomicAdd(&cnt[l >> 1], 1u << ((l & 1) << 4)); }
        if ((v.z >> RANGE_BITS) == r) { int l = v.z & (RANGE - 1); atomicAdd(&cnt[l >> 1], 1u << ((l & 1) << 4)); }
        if ((v.w >> RANGE_BITS) == r) { int l = v.w & (RANGE - 1); atomicAdd(&cnt[l >> 1], 1u << ((l & 1) << 4)); }
    }
    for (; e < e1; ++e) {
        const int idx = arr[e];
        if ((idx >> RANGE_BITS) == r) { int l = idx & (RANGE - 1); atomicAdd(&cnt[l >> 1], 1u << ((l & 1) << 4)); }
    }
    __syncthreads();
    for (int i = threadIdx.x; i < RANGE / 2; i += 256) part[i] = cnt[i];
}

// ---------------- reduce partials -> degrees/norms; dst partials -> slice prefixes ----------------
__global__ __launch_bounds__(256) void k_deg_reduce(unsigned int* __restrict__ pS,
                                                    unsigned int* __restrict__ pD,
                                                    float* __restrict__ out_norm,
                                                    float* __restrict__ in_norm,
                                                    int* __restrict__ in_deg, int N) {
    const int a = blockIdx.y;
    const int t = blockIdx.x * 256 + threadIdx.x;
    const int r = t >> (RANGE_BITS - 1);
    const int w = t & ((RANGE / 2) - 1);
    unsigned int* base = (a ? pD : pS) + (size_t)r * NSLICE * (RANGE / 2) + w;
    unsigned int lo = 0, hi = 0;
    if (a) {
        for (int s = 0; s < NSLICE; ++s) {
            const unsigned int v = base[(size_t)s * (RANGE / 2)];
            base[(size_t)s * (RANGE / 2)] = lo | (hi << 16);
            lo += v & 0xffffu; hi += v >> 16;
        }
    } else {
        for (int s = 0; s < NSLICE; ++s) {
            const unsigned int v = base[(size_t)s * (RANGE / 2)];
            lo += v & 0xffffu; hi += v >> 16;
        }
    }
    const int n0 = r * RANGE + 2 * w, n1 = n0 + 1;
    if (a) {
        if (n0 < N) { in_deg[n0] = (int)lo; in_norm[n0] = rsqrtf(fmaxf((float)lo, 1.f)); }
        if (n1 < N) { in_deg[n1] = (int)hi; in_norm[n1] = rsqrtf(fmaxf((float)hi, 1.f)); }
    } else {
        if (n0 < N) out_norm[n0] = rsqrtf(fmaxf((float)lo, 1.f));
        if (n1 < N) out_norm[n1] = rsqrtf(fmaxf((float)hi, 1.f));
    }
}

// ---------------- prefix-sum (3-phase) ----------------
__global__ __launch_bounds__(1024) void k_scan_block(const int* __restrict__ in,
                                                     int* __restrict__ row_ptr,
                                                     int* __restrict__ partials, int n) {
    __shared__ int sh[1024];
    int i = blockIdx.x * 1024 + threadIdx.x;
    int v = (i < n) ? in[i] : 0;
    sh[threadIdx.x] = v;
    __syncthreads();
    for (int off = 1; off < 1024; off <<= 1) {
        int t = (threadIdx.x >= off) ? sh[threadIdx.x - off] : 0;
        __syncthreads();
        sh[threadIdx.x] += t;
        __syncthreads();
    }
    if (i < n) row_ptr[i + 1] = sh[threadIdx.x];
    if (threadIdx.x == 1023) partials[blockIdx.x] = sh[1023];
}

__global__ __launch_bounds__(1024) void k_scan_partials(int* __restrict__ partials, int nb) {
    __shared__ int sh[1024];
    int v = (threadIdx.x < nb) ? partials[threadIdx.x] : 0;
    sh[threadIdx.x] = v;
    __syncthreads();
    for (int off = 1; off < 1024; off <<= 1) {
        int t = (threadIdx.x >= off) ? sh[threadIdx.x - off] : 0;
        __syncthreads();
        sh[threadIdx.x] += t;
        __syncthreads();
    }
    if (threadIdx.x < nb) partials[threadIdx.x] = sh[threadIdx.x] - v;
}

__global__ void k_scan_finalize(int* __restrict__ row_ptr, const int* __restrict__ partials,
                                int n) {
    int i = blockIdx.x * blockDim.x + threadIdx.x;
    if (i < n) {
        row_ptr[i + 1] += partials[i >> 10];
        if (i == 0) row_ptr[0] = 0;
    }
}

// ---------------- deterministic CSR scatter (no global atomics) ----------------
__global__ __launch_bounds__(256) void k_scatter_lds(const int* __restrict__ src,
                                                     const int* __restrict__ dst,
                                                     const unsigned int* __restrict__ pD,
                                                     const int* __restrict__ row_ptr,
                                                     int* __restrict__ ssrc, int E, int EPS) {
    __shared__ unsigned int cur[RANGE / 2];   // 32 KB
    const int r = blockIdx.x & 7;
    const int s = blockIdx.x >> 3;
    const unsigned int* pre = pD + ((size_t)r * NSLICE + s) * (RANGE / 2);
    for (int i = threadIdx.x; i < RANGE / 2; i += 256) cur[i] = pre[i];
    __syncthreads();
    const int e0 = s * EPS;
    const int e1 = min(E, e0 + EPS);
    int e = e0 + threadIdx.x * 4;
    for (; e + 3 < e1; e += 1024) {
        const int4 v = *(const int4*)&dst[e];
#pragma unroll
        for (int j = 0; j < 4; ++j) {
            const int d = (&v.x)[j];
            if ((d >> RANGE_BITS) == r) {
                const int local = d & (RANGE - 1);
                const int sh = (local & 1) << 4;
                const unsigned int old = atomicAdd(&cur[local >> 1], 1u << sh);
                const unsigned int off = (old >> sh) & 0xffffu;
                ssrc[row_ptr[d] + (int)off] = src[e + j];
            }
        }
    }
    for (; e < e1; ++e) {
        const int d = dst[e];
        if ((d >> RANGE_BITS) == r) {
            const int local = d & (RANGE - 1);
            const int sh = (local & 1) << 4;
            const unsigned int old = atomicAdd(&cur[local >> 1], 1u << sh);
            const unsigned int off = (old >> sh) & 0xffffu;
            ssrc[row_ptr[d] + (int)off] = src[e];
        }
    }
}

// ---------------- MFMA GEMM with rank-collapsed epilogues ----------------
// MODE 0 (gemm1, NW=2): out_table(fp8) = rowscale(X@W0); v[r] = (X@W1)[r] @ mlpW  (f32x2)
// MODE 1 (gemm2, NW=1): u[r] = rowscale(X@W0)[r] @ mlpW  (f32x2, no table)
template <typename TIN, int MODE>
__global__ __launch_bounds__(256) void gemm_mfma(const TIN* __restrict__ X,
                                                 const unsigned short* __restrict__ Wt0,
                                                 const unsigned short* __restrict__ Wt1,
                                                 const float* __restrict__ scale,
                                                 unsigned char* __restrict__ out_table,
                                                 float2* __restrict__ outv,
                                                 const float* __restrict__ mlpW,
                                                 int N) {
    constexpr int NW = (MODE == 0) ? 2 : 1;
    __shared__ unsigned short Ws[NW][128 * 128];   // 32 KB per weight
    const int tid = threadIdx.x;
#pragma unroll
    for (int w = 0; w < NW; ++w) {
        const unsigned short* Wsrc = w ? Wt1 : Wt0;
        for (int i = tid; i < 2048; i += 256) {
            const int n = i >> 4, b = i & 15;
            const uint4 v = *(const uint4*)&Wsrc[(size_t)n * 128 + b * 8];
            *(uint4*)&Ws[w][n * 128 + ((b ^ (n & 15)) << 3)] = v;
        }
    }
    __syncthreads();

    const int lane = tid & 63;
    const int wave = tid >> 6;
    const int quad = lane >> 4;
    const int l16 = lane & 15;
    const int r_base = blockIdx.x * 64 + wave * 16;
    const int ra = min(r_base + l16, N - 1);          // A-operand row (clamped)

    f4v acc[NW][8];
#pragma unroll
    for (int w = 0; w < NW; ++w)
#pragma unroll
        for (int nn = 0; nn < 8; ++nn) acc[w][nn] = (f4v)0.f;

    const TIN* xp = X + (size_t)ra * 128 + quad * 8;

#pragma unroll
    for (int kt = 0; kt < 4; ++kt) {
        s8v af;
        if constexpr (sizeof(TIN) == 4) {
            const float4 lo = *(const float4*)(xp + kt * 32);
            const float4 hi = *(const float4*)(xp + kt * 32 + 4);
            af[0] = (short)f2bf(lo.x); af[1] = (short)f2bf(lo.y);
            af[2] = (short)f2bf(lo.z); af[3] = (short)f2bf(lo.w);
            af[4] = (short)f2bf(hi.x); af[5] = (short)f2bf(hi.y);
            af[6] = (short)f2bf(hi.z); af[7] = (short)f2bf(hi.w);
        } else {
            af = *(const s8v*)(xp + kt * 32);
        }
#pragma unroll
        for (int nn = 0; nn < 8; ++nn) {
            const int bofs = (nn * 16 + l16) * 128 + (((kt * 4 + quad) ^ l16) << 3);
#pragma unroll
            for (int w = 0; w < NW; ++w) {
                const s8v bf = *(const s8v*)&Ws[w][bofs];
                acc[w][nn] = mfma16(af, bf, acc[w][nn]);
            }
        }
    }

    // epilogue: C/D layout col = nn*16 + l16, row = quad*4 + g
    const int rc = r_base + quad * 4;
    float sc[4];
#pragma unroll
    for (int g = 0; g < 4; ++g) sc[g] = scale[min(rc + g, N - 1)];

    if constexpr (MODE == 0) {
        // fp8 table from acc[0] * rowscale
#pragma unroll
        for (int nn = 0; nn < 8; ++nn) {
            const int col = nn * 16 + l16;
#pragma unroll
            for (int g = 0; g < 4; ++g) {
                const int r = rc + g;
                if (r < N) out_table[(size_t)r * 128 + col] = f2fp8(acc[0][nn][g] * sc[g]);
            }
        }
    }

    // rank-collapsed head: p[g] = sum_cols val[r,col] * mlpW[col][0..1]
    {
        float2 w2[8];
#pragma unroll
        for (int nn = 0; nn < 8; ++nn)
            w2[nn] = ((const float2*)mlpW)[nn * 16 + l16];
#pragma unroll
        for (int g = 0; g < 4; ++g) {
            float p0 = 0.f, p1 = 0.f;
#pragma unroll
            for (int nn = 0; nn < 8; ++nn) {
                float val;
                if constexpr (MODE == 0) val = acc[1][nn][g];        // residual path, no scale
                else                     val = acc[0][nn][g] * sc[g]; // t2 path, scaled (f32!)
                p0 = fmaf(val, w2[nn].x, p0);
                p1 = fmaf(val, w2[nn].y, p1);
            }
#pragma unroll
            for (int off = 1; off < 16; off <<= 1) {
                p0 += __shfl_xor(p0, off);
                p1 += __shfl_xor(p1, off);
            }
            const int r = rc + g;
            if (l16 == 0 && r < N) outv[r] = make_float2(p0, p1);
        }
    }
}

// ---------------- layer-1 CSR aggregation (fp8 gather, 4 loads in flight) ----------------
__global__ __launch_bounds__(256) void k_spmm1(const unsigned char* __restrict__ T,
                                               const int* __restrict__ row_ptr,
                                               const int* __restrict__ ssrc,
                                               const float* __restrict__ in_norm,
                                               const float* __restrict__ bias,
                                               unsigned short* __restrict__ Hout, int N) {
    const int lane = threadIdx.x & 63;
    const int grp = lane >> 4;        // edge group 0..3
    const int gl  = lane & 15;        // 8B column chunk within fp8 row
    const int d = blockIdx.x * 4 + (threadIdx.x >> 6);
    if (d >= N) return;

    const int start = row_ptr[d], end = row_ptr[d + 1];
    float acc[8];
#pragma unroll
    for (int j = 0; j < 8; ++j) acc[j] = 0.f;

    for (int base = start; base < end; base += 64) {
        const int cnt = min(64, end - base);
        const int sl = (lane < cnt) ? ssrc[base + lane] : 0;
        for (int i = 0; i < cnt; i += 16) {
            int   ss[4];
            float mm[4];
            uint2 ww[4];
#pragma unroll
            for (int u = 0; u < 4; ++u) {
                const int e = i + 4 * u + grp;
                ss[u] = __shfl(sl, min(e, cnt - 1));
                mm[u] = (e < cnt) ? 1.f : 0.f;
            }
#pragma unroll
            for (int u = 0; u < 4; ++u)
                ww[u] = *(const uint2*)&T[(size_t)ss[u] * 128 + gl * 8];
#pragma unroll
            for (int u = 0; u < 4; ++u) {
                const f2v a0 = __builtin_amdgcn_cvt_pk_f32_fp8(ww[u].x, false);
                const f2v a1 = __builtin_amdgcn_cvt_pk_f32_fp8(ww[u].x, true);
                const f2v a2 = __builtin_amdgcn_cvt_pk_f32_fp8(ww[u].y, false);
                const f2v a3 = __builtin_amdgcn_cvt_pk_f32_fp8(ww[u].y, true);
                const float m = mm[u];
                acc[0] = fmaf(m, a0[0], acc[0]); acc[1] = fmaf(m, a0[1], acc[1]);
                acc[2] = fmaf(m, a1[0], acc[2]); acc[3] = fmaf(m, a1[1], acc[3]);
                acc[4] = fmaf(m, a2[0], acc[4]); acc[5] = fmaf(m, a2[1], acc[5]);
                acc[6] = fmaf(m, a3[0], acc[6]); acc[7] = fmaf(m, a3[1], acc[7]);
            }
        }
    }

#pragma unroll
    for (int j = 0; j < 8; ++j) {
        acc[j] += __shfl_xor(acc[j], 16);
        acc[j] += __shfl_xor(acc[j], 32);
    }

    const float inr = in_norm[d];
    const float4 bb0 = *(const float4*)&bias[gl * 8];
    const float4 bb1 = *(const float4*)&bias[gl * 8 + 4];
    float v[8];
    v[0] = fmaxf(acc[0] * inr + bb0.x, 0.f); v[1] = fmaxf(acc[1] * inr + bb0.y, 0.f);
    v[2] = fmaxf(acc[2] * inr + bb0.z, 0.f); v[3] = fmaxf(acc[3] * inr + bb0.w, 0.f);
    v[4] = fmaxf(acc[4] * inr + bb1.x, 0.f); v[5] = fmaxf(acc[5] * inr + bb1.y, 0.f);
    v[6] = fmaxf(acc[6] * inr + bb1.z, 0.f); v[7] = fmaxf(acc[7] * inr + bb1.w, 0.f);

    if (grp == 0) {
        uint4 o;
        o.x = packbf(v[0], v[1]); o.y = packbf(v[2], v[3]);
        o.z = packbf(v[4], v[5]); o.w = packbf(v[6], v[7]);
        *(uint4*)&Hout[(size_t)d * 128 + gl * 8] = o;
    }
}

// ---------------- final: out[d] = in_norm[d]*sum(u[src]) + v[d] + K ----------------
// u table is N x 8B = 800 KB -> L2-resident gather. Thread per dst, 4-wide unroll.
__global__ __launch_bounds__(256) void k_final(const float2* __restrict__ u,
                                               const int* __restrict__ row_ptr,
                                               const int* __restrict__ ssrc,
                                               const float* __restrict__ in_norm,
                                               const float2* __restrict__ v,
                                               const float* __restrict__ K,
                                               float2* __restrict__ out, int N) {
    const int d = blockIdx.x * 256 + threadIdx.x;
    if (d >= N) return;
    const int start = row_ptr[d], end = row_ptr[d + 1];
    float sx = 0.f, sy = 0.f;
    int i = start;
    for (; i + 4 <= end; i += 4) {
        const int s0 = ssrc[i], s1 = ssrc[i + 1], s2 = ssrc[i + 2], s3 = ssrc[i + 3];
        const float2 u0 = u[s0], u1 = u[s1], u2 = u[s2], u3 = u[s3];
        sx += (u0.x + u1.x) + (u2.x + u3.x);
        sy += (u0.y + u1.y) + (u2.y + u3.y);
    }
    for (; i < end; ++i) {
        const float2 uu = u[ssrc[i]];
        sx += uu.x; sy += uu.y;
    }
    const float inr = in_norm[d];
    const float2 vv = v[d];
    out[d] = make_float2(sx * inr + vv.x + K[0], sy * inr + vv.y + K[1]);
}

// ---------------- launch ----------------
extern "C" void kernel_launch(void* const* d_in, const int* in_sizes, int n_in,
                              void* d_out, int out_size, void* d_ws, size_t ws_size,
                              hipStream_t stream) {
    const float* x     = (const float*)d_in[0];
    const int*   src   = (const int*)d_in[1];
    const int*   dst   = (const int*)d_in[2];
    const float* W1    = (const float*)d_in[3];
    const float* b1    = (const float*)d_in[4];
    const float* W2    = (const float*)d_in[5];
    const float* b2    = (const float*)d_in[6];
    const float* res_W = (const float*)d_in[7];
    const float* mlp_W = (const float*)d_in[8];
    const float* mlp_b = (const float*)d_in[9];
    float* out = (float*)d_out;

    const int N = in_sizes[0] / 128;
    const int E = in_sizes[1];
    const int EPS = (E + NSLICE - 1) / NSLICE;

    // workspace layout. partialS spans A (12.8MB) + first ~4MB of B; partialD sits
    // at B+4MB (16.8MB, ends < B end). Both dead before gemm1 writes A / spmm1
    // writes B (deg_reduce & scatter consume them earlier in the pipeline).
    char* p = (char*)d_ws;
    unsigned char*  A = (unsigned char*)p;   p += (size_t)N * 128;       // t1 fp8 table (12.8 MB)
    unsigned short* B = (unsigned short*)p;  p += (size_t)N * 128 * 2;   // h1 bf16 (25.6 MB)
    unsigned short* Wt = (unsigned short*)p; p += (size_t)3 * 16384 * 2; // Wt1|Wt2|Rt bf16
    float* out_norm = (float*)p;             p += (size_t)N * 4;
    float* in_norm  = (float*)p;             p += (size_t)N * 4;
    int* in_deg     = (int*)p;               p += (size_t)N * 4;
    int* row_ptr    = (int*)p;               p += (size_t)(N + 1) * 4;
    int* scanpart   = (int*)p;               p += (size_t)1024 * 4;
    float* Kc       = (float*)p;             p += (size_t)16;
    float2* v2      = (float2*)p;            p += (size_t)N * 8;         // (x@res_W)@mlpW
    float2* u2      = (float2*)p;            p += (size_t)N * 8;         // t2@mlpW
    int* ssrc       = (int*)p;               p += (size_t)E * 4;
    unsigned int* partialS = (unsigned int*)A;                            // 16.8 MB
    unsigned int* partialD = (unsigned int*)((char*)B + (size_t)4 * 1024 * 1024);

    const int gN = (N + 255) / 256;
    const int nb = (N + 1023) / 1024;
    const int gGemm = (N + 63) / 64;
    const int gSpmm = (N + 3) / 4;

    // 0. weight prep + head constant
    k_prep_w<<<dim3(3, 4), 256, 0, stream>>>(W1, W2, res_W, Wt);
    k_prep_k<<<1, 64, 0, stream>>>(b2, mlp_W, mlp_b, Kc);

    // 1. degrees + norms + slice prefixes (no global atomics)
    k_hist_lds<<<dim3(NR_PAD * NSLICE, 2), 256, 0, stream>>>(src, dst, partialS, partialD, E, EPS);
    k_deg_reduce<<<dim3(NR_PAD * (RANGE / 2) / 256, 2), 256, 0, stream>>>(partialS, partialD,
                                                                          out_norm, in_norm, in_deg, N);

    // 2. row_ptr scan + deterministic CSR scatter
    k_scan_block<<<nb, 1024, 0, stream>>>(in_deg, row_ptr, scanpart, N);
    k_scan_partials<<<1, 1024, 0, stream>>>(scanpart, nb);
    k_scan_finalize<<<gN, 256, 0, stream>>>(row_ptr, scanpart, N);
    k_scatter_lds<<<NR_PAD * NSLICE, 256, 0, stream>>>(src, dst, partialD, row_ptr, ssrc, E, EPS);

    // 3. gemm1: A(fp8) = rowscale(x@W1), v2 = (x@res_W)@mlpW  (C never materialized)
    gemm_mfma<float, 0><<<gGemm, 256, 0, stream>>>(x, Wt, Wt + 2 * 16384, out_norm,
                                                   A, v2, mlp_W, N);

    // 4. layer-1 aggregation: B = relu(agg(A)*in_norm + b1)
    k_spmm1<<<gSpmm, 256, 0, stream>>>(A, row_ptr, ssrc, in_norm, b1, B, N);

    // 5. gemm2: u2 = rowscale(B@W2)@mlpW  (rank-collapsed, f32 — no fp8 table)
    gemm_mfma<unsigned short, 1><<<gGemm, 256, 0, stream>>>(B, Wt + 16384, nullptr, out_norm,
                                                            nullptr, u2, mlp_W, N);

    // 6. final: out[d] = in_norm[d]*sum(u2[src]) + v2[d] + K   (800KB L2-resident gather)
    k_final<<<gN, 256, 0, stream>>>(u2, row_ptr, ssrc, in_norm, v2, Kc, (float2*)out, N);

    (void)n_in; (void)out_size; (void)ws_size;
}